// Round 1
// baseline (579.918 us; speedup 1.0000x reference)
//
#include <hip/hip_runtime.h>
#include <stdint.h>

typedef unsigned short u16;
typedef __attribute__((ext_vector_type(8))) short short8;   // 8 x bf16 (4 VGPRs)
typedef __attribute__((ext_vector_type(4))) float f32x4;    // MFMA accumulator

#define MFMA16(a,b,c) __builtin_amdgcn_mfma_f32_16x16x32_bf16((a),(b),(c),0,0,0)

__device__ __forceinline__ u16 f2bf(float f) {
  union { float f; uint32_t u; } v; v.f = f;
  uint32_t r = v.u + 0x7FFFu + ((v.u >> 16) & 1u);   // RNE
  return (u16)(r >> 16);
}
__device__ __forceinline__ float bf2f(u16 u) {
  union { uint32_t i; float f; } v; v.i = ((uint32_t)u) << 16; return v.f;
}
// async global->LDS, 16B per lane; LDS dest = wave-uniform base + lane*16
__device__ __forceinline__ void async_copy16(void* lds, const void* g) {
  __builtin_amdgcn_global_load_lds(
      (const __attribute__((address_space(1))) uint32_t*)g,
      (__attribute__((address_space(3))) uint32_t*)lds, 16, 0, 0);
}

// ---------------------------------------------------------------------------
// elementwise fp32 -> bf16 cast (4 elems/thread)
__global__ __launch_bounds__(256) void cast_bf16_kernel(
    const float* __restrict__ in, u16* __restrict__ out) {
  int i = blockIdx.x * 256 + threadIdx.x;
  float4 v = ((const float4*)in)[i];
  uint2 o;
  o.x = (uint32_t)f2bf(v.x) | ((uint32_t)f2bf(v.y) << 16);
  o.y = (uint32_t)f2bf(v.z) | ((uint32_t)f2bf(v.w) << 16);
  ((uint2*)out)[i] = o;
}

// transpose + cast: in fp32 [rows, cols] -> out bf16 [cols, rows]
__global__ __launch_bounds__(256) void transpose_cast(
    const float* __restrict__ in, u16* __restrict__ out, int rows, int cols) {
  __shared__ float tile[32][33];
  int c0 = blockIdx.x * 32, r0 = blockIdx.y * 32;
  int tx = threadIdx.x, ty = threadIdx.y;   // (32,8)
#pragma unroll
  for (int j = 0; j < 4; j++)
    tile[ty + j * 8][tx] = in[(size_t)(r0 + ty + j * 8) * cols + c0 + tx];
  __syncthreads();
#pragma unroll
  for (int j = 0; j < 4; j++)
    out[(size_t)(c0 + ty + j * 8) * rows + r0 + tx] = f2bf(tile[tx][ty + j * 8]);
}

__global__ void pack_bias3(const float* __restrict__ a, const float* __restrict__ b,
                           const float* __restrict__ c, float* __restrict__ o) {
  int i = blockIdx.x * 256 + threadIdx.x;  // 3072
  o[i] = (i < 1024) ? a[i] : (i < 2048 ? b[i - 1024] : c[i - 2048]);
}

// ---------------------------------------------------------------------------
// mod[b*16+h][s] = sigmoid(X[row]@cgW[:,h] + cgb[h] + cons@amW[:,h] + amb[h]) * 0.125
__global__ __launch_bounds__(256) void mod_kernel(
    const float* __restrict__ X, const float* __restrict__ cgW,
    const float* __restrict__ cgb, const float* __restrict__ cons,
    const float* __restrict__ amW, const float* __restrict__ amb,
    float* __restrict__ modp) {
  __shared__ float xs[1024];
  __shared__ float part[16][16];
  __shared__ float am[16];
  int row = blockIdx.x, t = threadIdx.x;
  {
    float4 v = ((const float4*)(X + (size_t)row * 1024))[t];
    xs[t * 4 + 0] = v.x; xs[t * 4 + 1] = v.y; xs[t * 4 + 2] = v.z; xs[t * 4 + 3] = v.w;
  }
  if (t < 16) {
    float a = amb[t];
#pragma unroll
    for (int i = 0; i < 16; i++) a += cons[i] * amW[i * 16 + t];
    am[t] = a;
  }
  __syncthreads();
  int h = t & 15, ch = t >> 4;
  float p = 0.f;
#pragma unroll 8
  for (int k = ch * 64; k < ch * 64 + 64; k++) p += xs[k] * cgW[k * 16 + h];
  part[ch][h] = p;
  __syncthreads();
  if (t < 16) {
    float s = cgb[t] + am[t];
#pragma unroll
    for (int c = 0; c < 16; c++) s += part[c][t];
    int b = row >> 10, si = row & 1023;
    modp[((size_t)(b * 16 + t)) * 1024 + si] = 0.125f / (1.f + __expf(-s));
  }
}

// ---------------------------------------------------------------------------
// m97-style bf16 GEMM: C[M,N] = A[M,K] @ Bt[N,K]^T (+bias, optional blend)
// 128x128 tile, BK=32, 4 waves each computing 64x64 (4x4 MFMA 16x16x32)
template <int OUT_F32, int HAS_EXTRA>
__global__ __launch_bounds__(256) void gemm_bt(
    const u16* __restrict__ A, const u16* __restrict__ Bt,
    const float* __restrict__ bias, const u16* __restrict__ extra,
    float alpha, float beta, void* __restrict__ Cout, int M, int N, int K) {
  __shared__ u16 As[128 * 32];
  __shared__ u16 Bs[128 * 32];
  const int t = threadIdx.x;
  const int w = t >> 6, l = t & 63, lm = l & 15, lg = l >> 4;
  const int wm = w & 1, wn = w >> 1;
  const int m0 = blockIdx.y * 128, n0 = blockIdx.x * 128;
  const f32x4 fzero = {0.f, 0.f, 0.f, 0.f};
  f32x4 acc[4][4];
#pragma unroll
  for (int i = 0; i < 4; i++)
#pragma unroll
    for (int j = 0; j < 4; j++) acc[i][j] = fzero;

  for (int kt = 0; kt < K; kt += 32) {
    __syncthreads();
#pragma unroll
    for (int c = 0; c < 2; c++) {
      int r = c * 64 + (t >> 2), col = (t & 3) * 8;
      async_copy16(&As[c * 2048 + w * 512], A + (size_t)(m0 + r) * K + kt + col);
      async_copy16(&Bs[c * 2048 + w * 512], Bt + (size_t)(n0 + r) * K + kt + col);
    }
    __syncthreads();  // drains vmcnt for global_load_lds
    short8 af[4], bf[4];
#pragma unroll
    for (int i = 0; i < 4; i++)
      af[i] = *(const short8*)&As[(wm * 64 + i * 16 + lm) * 32 + lg * 8];
#pragma unroll
    for (int j = 0; j < 4; j++)
      bf[j] = *(const short8*)&Bs[(wn * 64 + j * 16 + lm) * 32 + lg * 8];
#pragma unroll
    for (int i = 0; i < 4; i++)
#pragma unroll
      for (int j = 0; j < 4; j++) acc[i][j] = MFMA16(af[i], bf[j], acc[i][j]);
  }
  // epilogue: C-layout row=(lg*4+r), col=lm within each 16x16 tile
#pragma unroll
  for (int i = 0; i < 4; i++) {
    int row0 = m0 + wm * 64 + i * 16 + lg * 4;
#pragma unroll
    for (int j = 0; j < 4; j++) {
      int col = n0 + wn * 64 + j * 16 + lm;
      float bc = bias[col];
#pragma unroll
      for (int r = 0; r < 4; r++) {
        size_t idx = (size_t)(row0 + r) * N + col;
        float v = acc[i][j][r] + bc;
        if constexpr (HAS_EXTRA) v = alpha * v + beta * bf2f(extra[idx]);
        if constexpr (OUT_F32) ((float*)Cout)[idx] = v;
        else ((u16*)Cout)[idx] = f2bf(v);
      }
    }
  }
}

// ---------------------------------------------------------------------------
// MFMA flash attention, no mask, S=1024. qkv: bf16 [B*S, 3072], q|k|v at col
// 0|1024|2048, head h at +h*HD. 4 waves, BQ=64 (16 q-rows/wave).
// USE_MOD: per-row score scale from modp (already includes the 1/8), else `scale`.
template <int HD, int BKV, int USE_MOD>
__global__ __launch_bounds__(256) void flash_attn(
    const u16* __restrict__ qkv, const float* __restrict__ modp,
    u16* __restrict__ outp, float scale, int NH) {
  constexpr int S = 1024, W3 = 3072, Hh = 1024;
  constexpr int NKD = HD / 32;     // d-steps for QK^T
  constexpr int NT  = BKV / 16;    // col-subtiles of S
  constexpr int ND  = HD / 16;     // col-subtiles of O
  constexpr int NKP = BKV / 32;    // k-steps for PV
  constexpr int KC  = (BKV * HD) / 2048;      // staging rounds (2048 elems each)
  constexpr int VSTR = (BKV == 64) ? 72 : 40; // 16B-aligned rows, conflict-tuned
  constexpr int PSTR = VSTR;

  __shared__ u16 Ks[BKV * HD];       // XOR-swizzled on 8-elem granules
  __shared__ u16 Vt[HD * VSTR];      // V transposed: Vt[d][k]
  __shared__ u16 Ps[64 * PSTR];      // P in A-operand-friendly [q][k]

  const int t = threadIdx.x, w = t >> 6, l = t & 63, lm = l & 15, lg = l >> 4;
  const int bh = blockIdx.y, b = bh / NH, h = bh % NH;
  const int q0 = blockIdx.x * 64;
  const size_t rowbase = (size_t)b * S;

  // Q fragments live in registers (A-layout: row=lm, k=lg*8+j within 32-chunk)
  short8 qf[NKD];
  {
    const u16* qp = qkv + (rowbase + q0 + w * 16 + lm) * W3 + h * HD + lg * 8;
#pragma unroll
    for (int d = 0; d < NKD; d++) qf[d] = *(const short8*)(qp + d * 32);
  }
  float rs[4];
#pragma unroll
  for (int r = 0; r < 4; r++) {
    if constexpr (USE_MOD)
      rs[r] = modp[(size_t)bh * S + q0 + w * 16 + lg * 4 + r];
    else
      rs[r] = scale;
  }

  float m_i[4], l_i[4];
#pragma unroll
  for (int r = 0; r < 4; r++) { m_i[r] = -1e30f; l_i[r] = 0.f; }
  const f32x4 fzero = {0.f, 0.f, 0.f, 0.f};
  f32x4 oacc[ND];
#pragma unroll
  for (int d = 0; d < ND; d++) oacc[d] = fzero;

  for (int kb = 0; kb < S; kb += BKV) {
    __syncthreads();  // all waves done reading Ks/Vt from previous tile
    // ---- stage K tile with granule swizzle (coalesced global reads)
#pragma unroll
    for (int c = 0; c < KC; c++) {
      int e = (c * 256 + t) * 8;
      int kr = e / HD, g = (e % HD) / 8;
      short8 kv = *(const short8*)(qkv + (rowbase + kb + kr) * W3 + Hh + h * HD + g * 8);
      *(short8*)&Ks[kr * HD + (g ^ (kr & 7)) * 8] = kv;
    }
    // ---- stage V transposed (lane->row assignment keeps LDS writes spread)
#pragma unroll
    for (int c = 0; c < KC; c++) {
      int vr = t & (BKV - 1);
      int vc = c * (2048 / BKV) + (t / BKV) * 8;
      short8 vv = *(const short8*)(qkv + (rowbase + kb + vr) * W3 + 2 * Hh + h * HD + vc);
#pragma unroll
      for (int j = 0; j < 8; j++) Vt[(vc + j) * VSTR + vr] = (u16)vv[j];
    }
    __syncthreads();

    // ---- S = Q K^T  (C-layout: row=q=lg*4+r, col=k=n*16+lm)
    f32x4 sacc[NT];
#pragma unroll
    for (int n = 0; n < NT; n++) sacc[n] = fzero;
#pragma unroll
    for (int n = 0; n < NT; n++) {
      int krow = n * 16 + lm;
#pragma unroll
      for (int d = 0; d < NKD; d++) {
        int g = d * 4 + lg;
        short8 kf = *(const short8*)&Ks[krow * HD + (g ^ (krow & 7)) * 8];
        sacc[n] = MFMA16(qf[d], kf, sacc[n]);
      }
    }
    // ---- online softmax (row stats across 16-lane col group)
    float alpha_[4];
    float p[NT][4];
#pragma unroll
    for (int r = 0; r < 4; r++) {
      float mx = -1e30f;
#pragma unroll
      for (int n = 0; n < NT; n++) { float v = sacc[n][r] * rs[r]; p[n][r] = v; mx = fmaxf(mx, v); }
#pragma unroll
      for (int s = 8; s >= 1; s >>= 1) mx = fmaxf(mx, __shfl_xor(mx, s));
      float mnew = fmaxf(m_i[r], mx);
      alpha_[r] = __expf(m_i[r] - mnew);
      float sum = 0.f;
#pragma unroll
      for (int n = 0; n < NT; n++) { float e = __expf(p[n][r] - mnew); p[n][r] = e; sum += e; }
#pragma unroll
      for (int s = 8; s >= 1; s >>= 1) sum += __shfl_xor(sum, s);
      l_i[r] = l_i[r] * alpha_[r] + sum;
      m_i[r] = mnew;
    }
#pragma unroll
    for (int d = 0; d < ND; d++)
#pragma unroll
      for (int r = 0; r < 4; r++) oacc[d][r] *= alpha_[r];
    // ---- P -> LDS (bf16), same-wave rows only: no barrier needed
#pragma unroll
    for (int n = 0; n < NT; n++)
#pragma unroll
      for (int r = 0; r < 4; r++)
        Ps[(w * 16 + lg * 4 + r) * PSTR + n * 16 + lm] = f2bf(p[n][r]);
    // ---- O += P V
#pragma unroll
    for (int ks = 0; ks < NKP; ks++) {
      short8 pf = *(const short8*)&Ps[(w * 16 + lm) * PSTR + ks * 32 + lg * 8];
#pragma unroll
      for (int d = 0; d < ND; d++) {
        short8 vf = *(const short8*)&Vt[(d * 16 + lm) * VSTR + ks * 32 + lg * 8];
        oacc[d] = MFMA16(pf, vf, oacc[d]);
      }
    }
  }
  // ---- epilogue: O / l, store bf16 [B*S, 1024] (heads interleaved)
#pragma unroll
  for (int d = 0; d < ND; d++) {
    int col = h * HD + d * 16 + lm;
#pragma unroll
    for (int r = 0; r < 4; r++) {
      int row = q0 + w * 16 + lg * 4 + r;
      outp[(rowbase + row) * 1024 + col] = f2bf(oacc[d][r] / l_i[r]);
    }
  }
}

// ---------------------------------------------------------------------------
extern "C" void kernel_launch(void* const* d_in, const int* in_sizes, int n_in,
                              void* d_out, int out_size, void* d_ws, size_t ws_size,
                              hipStream_t stream) {
  (void)in_sizes; (void)n_in; (void)out_size; (void)ws_size;
  const float* X      = (const float*)d_in[0];
  const float* cons   = (const float*)d_in[1];
  const float* Wq     = (const float*)d_in[2];  const float* bq     = (const float*)d_in[3];
  const float* Wk     = (const float*)d_in[4];  const float* bk     = (const float*)d_in[5];
  const float* Wv     = (const float*)d_in[6];  const float* bv     = (const float*)d_in[7];
  const float* cgW    = (const float*)d_in[8];  const float* cgb    = (const float*)d_in[9];
  const float* amW    = (const float*)d_in[10]; const float* amb    = (const float*)d_in[11];
  const float* caWin  = (const float*)d_in[12]; const float* cabin  = (const float*)d_in[13];
  const float* caWout = (const float*)d_in[14]; const float* cabout = (const float*)d_in[15];
  const float* mcWin  = (const float*)d_in[16]; const float* mcbin  = (const float*)d_in[17];
  const float* mcWout = (const float*)d_in[18]; const float* mcbout = (const float*)d_in[19];
  const float* Wo     = (const float*)d_in[20]; const float* bo     = (const float*)d_in[21];

  char* ws = (char*)d_ws;
  size_t off = 0;
  auto alloc = [&](size_t bytes) -> void* {
    void* p = ws + off; off += (bytes + 255) & ~(size_t)255; return p;
  };
  u16*   Xbf     = (u16*)alloc((size_t)4096 * 1024 * 2);
  u16*   WqkvT   = (u16*)alloc((size_t)3072 * 1024 * 2);
  u16*   caWinT  = (u16*)alloc((size_t)3072 * 1024 * 2);
  u16*   mcWinT  = (u16*)alloc((size_t)3072 * 1024 * 2);
  u16*   caWoutT = (u16*)alloc((size_t)1024 * 1024 * 2);
  u16*   mcWoutT = (u16*)alloc((size_t)1024 * 1024 * 2);
  u16*   WoT     = (u16*)alloc((size_t)1024 * 1024 * 2);
  float* bqkv    = (float*)alloc(3072 * 4);
  float* modb    = (float*)alloc((size_t)64 * 1024 * 4);
  u16*   big0    = (u16*)alloc((size_t)4096 * 3072 * 2);  // CAqkv -> QKVm -> MCqkv
  u16*   actx    = (u16*)alloc((size_t)4096 * 1024 * 2);
  u16*   ctxm    = (u16*)alloc((size_t)4096 * 1024 * 2);
  u16*   ctx1    = (u16*)alloc((size_t)4096 * 1024 * 2);
  u16*   mctx    = (u16*)alloc((size_t)4096 * 1024 * 2);
  u16*   ctx2    = (u16*)alloc((size_t)4096 * 1024 * 2);

  dim3 tb(32, 8);
  cast_bf16_kernel<<<4096, 256, 0, stream>>>(X, Xbf);
  transpose_cast<<<dim3(32, 32), tb, 0, stream>>>(Wq, WqkvT, 1024, 1024);
  transpose_cast<<<dim3(32, 32), tb, 0, stream>>>(Wk, WqkvT + (size_t)1024 * 1024, 1024, 1024);
  transpose_cast<<<dim3(32, 32), tb, 0, stream>>>(Wv, WqkvT + (size_t)2048 * 1024, 1024, 1024);
  transpose_cast<<<dim3(96, 32), tb, 0, stream>>>(caWin, caWinT, 1024, 3072);
  transpose_cast<<<dim3(32, 32), tb, 0, stream>>>(caWout, caWoutT, 1024, 1024);
  transpose_cast<<<dim3(96, 32), tb, 0, stream>>>(mcWin, mcWinT, 1024, 3072);
  transpose_cast<<<dim3(32, 32), tb, 0, stream>>>(mcWout, mcWoutT, 1024, 1024);
  transpose_cast<<<dim3(32, 32), tb, 0, stream>>>(Wo, WoT, 1024, 1024);
  pack_bias3<<<12, 256, 0, stream>>>(bq, bk, bv, bqkv);
  mod_kernel<<<4096, 256, 0, stream>>>(X, cgW, cgb, cons, amW, amb, modb);

  // causal branch in-proj, then its attention (frees big0 for main QKV)
  gemm_bt<0, 0><<<dim3(24, 32), 256, 0, stream>>>(Xbf, caWinT, cabin, nullptr, 0.f, 0.f,
                                                  big0, 4096, 3072, 1024);
  flash_attn<256, 32, 0><<<dim3(16, 16), 256, 0, stream>>>(big0, nullptr, actx, 1.f / 16.f, 4);
  // main QKV + gated attention
  gemm_bt<0, 0><<<dim3(24, 32), 256, 0, stream>>>(Xbf, WqkvT, bqkv, nullptr, 0.f, 0.f,
                                                  big0, 4096, 3072, 1024);
  flash_attn<64, 64, 1><<<dim3(16, 64), 256, 0, stream>>>(big0, modb, ctxm, 1.f, 16);
  // ctx1 = 0.3*ctxm + 0.7*(actx@caWout + cabout)
  gemm_bt<0, 1><<<dim3(8, 32), 256, 0, stream>>>(actx, caWoutT, cabout, ctxm, 0.7f, 0.3f,
                                                 ctx1, 4096, 1024, 1024);
  // meta branch
  gemm_bt<0, 0><<<dim3(24, 32), 256, 0, stream>>>(ctx1, mcWinT, mcbin, nullptr, 0.f, 0.f,
                                                  big0, 4096, 3072, 1024);
  flash_attn<256, 32, 0><<<dim3(16, 16), 256, 0, stream>>>(big0, nullptr, mctx, 1.f / 16.f, 4);
  // ctx2 = 0.85*ctx1 + 0.15*(mctx@mcWout + mcbout)
  gemm_bt<0, 1><<<dim3(8, 32), 256, 0, stream>>>(mctx, mcWoutT, mcbout, ctx1, 0.15f, 0.85f,
                                                 ctx2, 4096, 1024, 1024);
  // out = ctx2@Wo + bo (fp32)
  gemm_bt<1, 0><<<dim3(8, 32), 256, 0, stream>>>(ctx2, WoT, bo, nullptr, 0.f, 0.f,
                                                 d_out, 4096, 1024, 1024);
}

// Round 2
// 579.829 us; speedup vs baseline: 1.0002x; 1.0002x over previous
//
#include <hip/hip_runtime.h>
#include <stdint.h>

typedef unsigned short u16;
typedef __attribute__((ext_vector_type(8))) short short8;   // 8 x bf16 (4 VGPRs)
typedef __attribute__((ext_vector_type(4))) float f32x4;    // MFMA accumulator

#define MFMA16(a,b,c) __builtin_amdgcn_mfma_f32_16x16x32_bf16((a),(b),(c),0,0,0)

__device__ __forceinline__ u16 f2bf(float f) {
  union { float f; uint32_t u; } v; v.f = f;
  uint32_t r = v.u + 0x7FFFu + ((v.u >> 16) & 1u);   // RNE
  return (u16)(r >> 16);
}
__device__ __forceinline__ float bf2f(uint32_t u) {
  union { uint32_t i; float f; } v; v.i = u << 16; return v.f;
}
// async global->LDS, 16B per lane; LDS dest = wave-uniform base + lane*16
__device__ __forceinline__ void async_copy16(void* lds, const void* g) {
  __builtin_amdgcn_global_load_lds(
      (const __attribute__((address_space(1))) uint32_t*)g,
      (__attribute__((address_space(3))) uint32_t*)lds, 16, 0, 0);
}

// in-register 8x8 u16 transpose across 8 lanes (lane8 = lane&7), 4 u32 regs
__device__ __forceinline__ void transpose8x8(uint32_t r[4], int lane8) {
  uint32_t a0, a1, a2, a3;
  a0 = __shfl_xor(r[0], 4); a1 = __shfl_xor(r[1], 4);
  a2 = __shfl_xor(r[2], 4); a3 = __shfl_xor(r[3], 4);
  if (lane8 & 4) { r[0] = a2; r[1] = a3; } else { r[2] = a0; r[3] = a1; }
  a0 = __shfl_xor(r[0], 2); a1 = __shfl_xor(r[1], 2);
  a2 = __shfl_xor(r[2], 2); a3 = __shfl_xor(r[3], 2);
  if (lane8 & 2) { r[0] = a1; r[2] = a3; } else { r[1] = a0; r[3] = a2; }
  a0 = __shfl_xor(r[0], 1); a1 = __shfl_xor(r[1], 1);
  a2 = __shfl_xor(r[2], 1); a3 = __shfl_xor(r[3], 1);
  uint32_t sel = (lane8 & 1) ? 0x03020706u : 0x05040100u;
  r[0] = __builtin_amdgcn_perm(a0, r[0], sel);
  r[1] = __builtin_amdgcn_perm(a1, r[1], sel);
  r[2] = __builtin_amdgcn_perm(a2, r[2], sel);
  r[3] = __builtin_amdgcn_perm(a3, r[3], sel);
}

// ---------------------------------------------------------------------------
__global__ __launch_bounds__(256) void cast_bf16_kernel(
    const float* __restrict__ in, u16* __restrict__ out) {
  int i = blockIdx.x * 256 + threadIdx.x;
  float4 v = ((const float4*)in)[i];
  uint2 o;
  o.x = (uint32_t)f2bf(v.x) | ((uint32_t)f2bf(v.y) << 16);
  o.y = (uint32_t)f2bf(v.z) | ((uint32_t)f2bf(v.w) << 16);
  ((uint2*)out)[i] = o;
}

// batched transpose+cast: src fp32 [rows, cols] -> dst bf16 [cols, rows]
struct TBatch { const float* src[6]; u16* dst[6]; };
__global__ __launch_bounds__(256) void transpose_cast_batch(
    TBatch p, int rows, int cols) {
  __shared__ float tile[32][33];
  const float* __restrict__ in = p.src[blockIdx.z];
  u16* __restrict__ out = p.dst[blockIdx.z];
  int c0 = blockIdx.x * 32, r0 = blockIdx.y * 32;
  int tx = threadIdx.x, ty = threadIdx.y;   // (32,8)
#pragma unroll
  for (int j = 0; j < 4; j++)
    tile[ty + j * 8][tx] = in[(size_t)(r0 + ty + j * 8) * cols + c0 + tx];
  __syncthreads();
#pragma unroll
  for (int j = 0; j < 4; j++)
    out[(size_t)(c0 + ty + j * 8) * rows + r0 + tx] = f2bf(tile[tx][ty + j * 8]);
}

__global__ void pack_bias3(const float* __restrict__ a, const float* __restrict__ b,
                           const float* __restrict__ c, float* __restrict__ o) {
  int i = blockIdx.x * 256 + threadIdx.x;  // 3072
  o[i] = (i < 1024) ? a[i] : (i < 2048 ? b[i - 1024] : c[i - 2048]);
}

// ---------------------------------------------------------------------------
// mod[b*16+h][s] = sigmoid(X[row]@cgW[:,h] + cgb[h] + cons@amW[:,h] + amb[h]) / 8
__global__ __launch_bounds__(256) void mod_kernel(
    const float* __restrict__ X, const float* __restrict__ cgW,
    const float* __restrict__ cgb, const float* __restrict__ cons,
    const float* __restrict__ amW, const float* __restrict__ amb,
    float* __restrict__ modp) {
  __shared__ float xs[1024];
  __shared__ float part[16][16];
  __shared__ float am[16];
  int row = blockIdx.x, t = threadIdx.x;
  {
    float4 v = ((const float4*)(X + (size_t)row * 1024))[t];
    xs[t * 4 + 0] = v.x; xs[t * 4 + 1] = v.y; xs[t * 4 + 2] = v.z; xs[t * 4 + 3] = v.w;
  }
  if (t < 16) {
    float a = amb[t];
#pragma unroll
    for (int i = 0; i < 16; i++) a += cons[i] * amW[i * 16 + t];
    am[t] = a;
  }
  __syncthreads();
  int h = t & 15, ch = t >> 4;
  float p = 0.f;
#pragma unroll 8
  for (int k = ch * 64; k < ch * 64 + 64; k++) p += xs[k] * cgW[k * 16 + h];
  part[ch][h] = p;
  __syncthreads();
  if (t < 16) {
    float s = cgb[t] + am[t];
#pragma unroll
    for (int c = 0; c < 16; c++) s += part[c][t];
    int b = row >> 10, si = row & 1023;
    modp[((size_t)(b * 16 + t)) * 1024 + si] = 0.125f / (1.f + __expf(-s));
  }
}

// ---------------------------------------------------------------------------
// m97-style bf16 GEMM: C[M,N] = A[M,K] @ Bt[N,K]^T (+bias, optional blend)
// 128xBN tile, BK=32, 4 waves (BN=128: 64x64/wave; BN=64: 64x32/wave)
template <int OUT_F32, int HAS_EXTRA, int BN>
__global__ __launch_bounds__(256) void gemm_bt(
    const u16* __restrict__ A, const u16* __restrict__ Bt,
    const float* __restrict__ bias, const u16* __restrict__ extra,
    float alpha, float beta, void* __restrict__ Cout, int M, int N, int K) {
  constexpr int NJ = BN / 32;   // j-tiles per wave
  __shared__ u16 As[128 * 32];
  __shared__ u16 Bs[BN * 32];
  const int t = threadIdx.x;
  const int w = t >> 6, l = t & 63, lm = l & 15, lg = l >> 4;
  const int wm = w & 1, wn = w >> 1;
  const int m0 = blockIdx.y * 128, n0 = blockIdx.x * BN;
  const f32x4 fzero = {0.f, 0.f, 0.f, 0.f};
  f32x4 acc[4][NJ];
#pragma unroll
  for (int i = 0; i < 4; i++)
#pragma unroll
    for (int j = 0; j < NJ; j++) acc[i][j] = fzero;

  for (int kt = 0; kt < K; kt += 32) {
    __syncthreads();
#pragma unroll
    for (int c = 0; c < 2; c++) {
      int r = c * 64 + (t >> 2), col = (t & 3) * 8;
      async_copy16(&As[c * 2048 + w * 512], A + (size_t)(m0 + r) * K + kt + col);
    }
#pragma unroll
    for (int c = 0; c < BN / 64; c++) {
      int r = c * 64 + (t >> 2), col = (t & 3) * 8;
      async_copy16(&Bs[c * 2048 + w * 512], Bt + (size_t)(n0 + r) * K + kt + col);
    }
    __syncthreads();  // drains vmcnt for global_load_lds
    short8 af[4], bf[NJ];
#pragma unroll
    for (int i = 0; i < 4; i++)
      af[i] = *(const short8*)&As[(wm * 64 + i * 16 + lm) * 32 + lg * 8];
#pragma unroll
    for (int j = 0; j < NJ; j++)
      bf[j] = *(const short8*)&Bs[(wn * (BN / 2) + j * 16 + lm) * 32 + lg * 8];
#pragma unroll
    for (int i = 0; i < 4; i++)
#pragma unroll
      for (int j = 0; j < NJ; j++) acc[i][j] = MFMA16(af[i], bf[j], acc[i][j]);
  }
  // epilogue: C-layout row=(lg*4+r), col=lm within each 16x16 tile
#pragma unroll
  for (int i = 0; i < 4; i++) {
    int row0 = m0 + wm * 64 + i * 16 + lg * 4;
#pragma unroll
    for (int j = 0; j < NJ; j++) {
      int col = n0 + wn * (BN / 2) + j * 16 + lm;
      float bc = bias[col];
#pragma unroll
      for (int r = 0; r < 4; r++) {
        size_t idx = (size_t)(row0 + r) * N + col;
        float v = acc[i][j][r] + bc;
        if constexpr (HAS_EXTRA) v = alpha * v + beta * bf2f(extra[idx]);
        if constexpr (OUT_F32) ((float*)Cout)[idx] = v;
        else ((u16*)Cout)[idx] = f2bf(v);
      }
    }
  }
}

// ---------------------------------------------------------------------------
// MFMA flash attention, no mask, S=1024. qkv: bf16 [B*S, 3072], q|k|v at col
// 0|1024|2048, head h at +h*HD. 4 waves, BQ=64 (16 q-rows/wave).
// SPLIT>1: block handles kv slice z*(S/SPLIT).., writes unnormalized O (bf16)
// + per-row (m,l) partials for a separate merge pass.
template <int HD, int BKV, int USE_MOD, int SPLIT>
__global__ __launch_bounds__(256) void flash_attn(
    const u16* __restrict__ qkv, const float* __restrict__ modp,
    u16* __restrict__ outp, float2* __restrict__ ml, float scale, int NH) {
  constexpr int S = 1024, W3 = 3072, Hh = 1024;
  constexpr int NKD = HD / 32;     // d-steps for QK^T
  constexpr int NT  = BKV / 16;    // col-subtiles of S
  constexpr int ND  = HD / 16;     // col-subtiles of O
  constexpr int NKP = BKV / 32;    // k-steps for PV
  constexpr int KC  = (BKV * HD) / 2048;      // staging rounds (2048 elems each)
  constexpr int VSTR = (BKV == 64) ? 72 : 40; // 16B-aligned rows, padded
  constexpr int PSTR = VSTR;
  constexpr int KVLEN = S / SPLIT;
  constexpr int OPR = HD / 8;      // d-octets per V row
  constexpr int KVR = 2048 / HD;   // kv rows staged per round

  __shared__ u16 Ks[BKV * HD];     // XOR-swizzled on 8-elem granules
  __shared__ u16 Vt[HD * VSTR];    // V transposed: Vt[d][k]
  __shared__ u16 Ps[64 * PSTR];    // P in A-operand layout [q][k]

  const int t = threadIdx.x, w = t >> 6, l = t & 63, lm = l & 15, lg = l >> 4;
  const int bh = blockIdx.y, b = bh / NH, h = bh % NH;
  const int q0 = blockIdx.x * 64;
  const int z = (SPLIT > 1) ? blockIdx.z : 0;
  const size_t rowbase = (size_t)b * S;

  // V staging geometry: octet oc, lane-in-octet kvo
  const int oc = t >> 3, kvo = t & 7;
  const int sd0 = (oc % OPR) * 8;        // d octet base
  const int skvg = (oc / OPR) * 8;       // kv group base within round

  // Q fragments in registers (A-layout: row=lm, k=lg*8+j within 32-chunk)
  short8 qf[NKD];
  {
    const u16* qp = qkv + (rowbase + q0 + w * 16 + lm) * W3 + h * HD + lg * 8;
#pragma unroll
    for (int d = 0; d < NKD; d++) qf[d] = *(const short8*)(qp + d * 32);
  }
  float rs[4];
#pragma unroll
  for (int r = 0; r < 4; r++) {
    if constexpr (USE_MOD)
      rs[r] = modp[(size_t)bh * S + q0 + w * 16 + lg * 4 + r];
    else
      rs[r] = scale;
  }

  float m_i[4], l_i[4];
#pragma unroll
  for (int r = 0; r < 4; r++) { m_i[r] = -1e30f; l_i[r] = 0.f; }
  const f32x4 fzero = {0.f, 0.f, 0.f, 0.f};
  f32x4 oacc[ND];
#pragma unroll
  for (int d = 0; d < ND; d++) oacc[d] = fzero;

  for (int kb = z * KVLEN; kb < z * KVLEN + KVLEN; kb += BKV) {
    __syncthreads();  // all waves done reading Ks/Vt from previous tile
    // ---- stage K tile (granule-swizzled, coalesced, b128 writes)
#pragma unroll
    for (int c = 0; c < KC; c++) {
      int e = (c * 256 + t) * 8;
      int kr = e / HD, g = (e % HD) / 8;
      short8 kv = *(const short8*)(qkv + (rowbase + kb + kr) * W3 + Hh + h * HD + g * 8);
      *(short8*)&Ks[kr * HD + (g ^ (kr & 7)) * 8] = kv;
    }
    // ---- stage V transposed via in-register 8x8 butterfly (b128 writes)
#pragma unroll
    for (int c = 0; c < KC; c++) {
      int kv = c * KVR + skvg + kvo;
      union { short8 s; uint32_t u[4]; } vv, vo;
      vv.s = *(const short8*)(qkv + (rowbase + kb + kv) * W3 + 2 * Hh + h * HD + sd0);
      uint32_t r[4] = {vv.u[0], vv.u[1], vv.u[2], vv.u[3]};
      transpose8x8(r, kvo);
      vo.u[0] = r[0]; vo.u[1] = r[1]; vo.u[2] = r[2]; vo.u[3] = r[3];
      *(short8*)&Vt[(sd0 + kvo) * VSTR + c * KVR + skvg] = vo.s;
    }
    __syncthreads();

    // ---- S = Q K^T  (C-layout: row=q=lg*4+r, col=k=n*16+lm)
    f32x4 sacc[NT];
#pragma unroll
    for (int n = 0; n < NT; n++) sacc[n] = fzero;
#pragma unroll
    for (int n = 0; n < NT; n++) {
      int krow = n * 16 + lm;
#pragma unroll
      for (int d = 0; d < NKD; d++) {
        int g = d * 4 + lg;
        short8 kf = *(const short8*)&Ks[krow * HD + (g ^ (krow & 7)) * 8];
        sacc[n] = MFMA16(qf[d], kf, sacc[n]);
      }
    }
    // ---- online softmax (row stats across 16-lane col group)
    float alpha_[4];
    float p[NT][4];
#pragma unroll
    for (int r = 0; r < 4; r++) {
      float mx = -1e30f;
#pragma unroll
      for (int n = 0; n < NT; n++) { float v = sacc[n][r] * rs[r]; p[n][r] = v; mx = fmaxf(mx, v); }
#pragma unroll
      for (int s = 8; s >= 1; s >>= 1) mx = fmaxf(mx, __shfl_xor(mx, s));
      float mnew = fmaxf(m_i[r], mx);
      alpha_[r] = __expf(m_i[r] - mnew);
      float sum = 0.f;
#pragma unroll
      for (int n = 0; n < NT; n++) { float e = __expf(p[n][r] - mnew); p[n][r] = e; sum += e; }
#pragma unroll
      for (int s = 8; s >= 1; s >>= 1) sum += __shfl_xor(sum, s);
      l_i[r] = l_i[r] * alpha_[r] + sum;
      m_i[r] = mnew;
    }
#pragma unroll
    for (int d = 0; d < ND; d++)
#pragma unroll
      for (int r = 0; r < 4; r++) oacc[d][r] *= alpha_[r];
    // ---- P -> LDS (bf16), same-wave rows only: no barrier needed
#pragma unroll
    for (int n = 0; n < NT; n++)
#pragma unroll
      for (int r = 0; r < 4; r++)
        Ps[(w * 16 + lg * 4 + r) * PSTR + n * 16 + lm] = f2bf(p[n][r]);
    // ---- O += P V
#pragma unroll
    for (int ks = 0; ks < NKP; ks++) {
      short8 pf = *(const short8*)&Ps[(w * 16 + lm) * PSTR + ks * 32 + lg * 8];
#pragma unroll
      for (int d = 0; d < ND; d++) {
        short8 vf = *(const short8*)&Vt[(d * 16 + lm) * VSTR + ks * 32 + lg * 8];
        oacc[d] = MFMA16(pf, vf, oacc[d]);
      }
    }
  }
  // ---- epilogue
  if constexpr (SPLIT > 1) {
    // partial: unnormalized O (bf16) + per-row (m, l)
    const size_t obase = ((size_t)(z * 16 + bh)) << 10;
#pragma unroll
    for (int d = 0; d < ND; d++) {
      int col = d * 16 + lm;
#pragma unroll
      for (int r = 0; r < 4; r++) {
        int row = q0 + w * 16 + lg * 4 + r;
        outp[(obase + row) * HD + col] = f2bf(oacc[d][r]);
      }
    }
    if (lm == 0) {
#pragma unroll
      for (int r = 0; r < 4; r++) {
        int row = q0 + w * 16 + lg * 4 + r;
        ml[obase + row] = make_float2(m_i[r], l_i[r]);
      }
    }
  } else {
    // final: O / l, store bf16 [B*S, 1024] (heads interleaved)
#pragma unroll
    for (int d = 0; d < ND; d++) {
      int col = h * HD + d * 16 + lm;
#pragma unroll
      for (int r = 0; r < 4; r++) {
        int row = q0 + w * 16 + lg * 4 + r;
        outp[(rowbase + row) * 1024 + col] = f2bf(oacc[d][r] / l_i[r]);
      }
    }
  }
}

// ---------------------------------------------------------------------------
// merge SPLIT kv-partials (HD=256 branches): out = sum_s a_s O_s / sum_s a_s l_s
template <int SPLIT>
__global__ __launch_bounds__(256) void flash_merge(
    const u16* __restrict__ Opart, const float2* __restrict__ ml,
    u16* __restrict__ outp, int NH) {
  constexpr int NBH = 16;
  const int t = threadIdx.x;
  const int r8 = t >> 5, cg = t & 31;          // 8 rows x 32 col-groups
  const int R = blockIdx.x * 8 + r8;           // 0..16383
  const int bh = R >> 10, srow = R & 1023;
  const int b = bh / NH, h = bh % NH;
  float2 msl[SPLIT];
  float M = -1e30f;
#pragma unroll
  for (int s = 0; s < SPLIT; s++) {
    msl[s] = ml[(((size_t)(s * NBH + bh)) << 10) + srow];
    M = fmaxf(M, msl[s].x);
  }
  float L = 0.f, wgt[SPLIT];
#pragma unroll
  for (int s = 0; s < SPLIT; s++) { wgt[s] = __expf(msl[s].x - M); L += wgt[s] * msl[s].y; }
  const float inv = 1.f / L;
  float acc[8] = {0.f, 0.f, 0.f, 0.f, 0.f, 0.f, 0.f, 0.f};
#pragma unroll
  for (int s = 0; s < SPLIT; s++) {
    const u16* p = Opart + ((((size_t)(s * NBH + bh)) << 10) + srow) * 256 + cg * 8;
    uint4 v = *(const uint4*)p;
    float ws = wgt[s];
    acc[0] += ws * bf2f(v.x & 0xffffu); acc[1] += ws * bf2f(v.x >> 16);
    acc[2] += ws * bf2f(v.y & 0xffffu); acc[3] += ws * bf2f(v.y >> 16);
    acc[4] += ws * bf2f(v.z & 0xffffu); acc[5] += ws * bf2f(v.z >> 16);
    acc[6] += ws * bf2f(v.w & 0xffffu); acc[7] += ws * bf2f(v.w >> 16);
  }
  u16 o[8];
#pragma unroll
  for (int j = 0; j < 8; j++) o[j] = f2bf(acc[j] * inv);
  *(uint4*)&outp[((size_t)(b * 1024 + srow)) * 1024 + h * 256 + cg * 8] = *(const uint4*)o;
}

// ---------------------------------------------------------------------------
extern "C" void kernel_launch(void* const* d_in, const int* in_sizes, int n_in,
                              void* d_out, int out_size, void* d_ws, size_t ws_size,
                              hipStream_t stream) {
  (void)in_sizes; (void)n_in; (void)out_size; (void)ws_size;
  const float* X      = (const float*)d_in[0];
  const float* cons   = (const float*)d_in[1];
  const float* Wq     = (const float*)d_in[2];  const float* bq     = (const float*)d_in[3];
  const float* Wk     = (const float*)d_in[4];  const float* bk     = (const float*)d_in[5];
  const float* Wv     = (const float*)d_in[6];  const float* bv     = (const float*)d_in[7];
  const float* cgW    = (const float*)d_in[8];  const float* cgb    = (const float*)d_in[9];
  const float* amW    = (const float*)d_in[10]; const float* amb    = (const float*)d_in[11];
  const float* caWin  = (const float*)d_in[12]; const float* cabin  = (const float*)d_in[13];
  const float* caWout = (const float*)d_in[14]; const float* cabout = (const float*)d_in[15];
  const float* mcWin  = (const float*)d_in[16]; const float* mcbin  = (const float*)d_in[17];
  const float* mcWout = (const float*)d_in[18]; const float* mcbout = (const float*)d_in[19];
  const float* Wo     = (const float*)d_in[20]; const float* bo     = (const float*)d_in[21];

  char* ws = (char*)d_ws;
  size_t off = 0;
  auto alloc = [&](size_t bytes) -> void* {
    void* p = ws + off; off += (bytes + 255) & ~(size_t)255; return p;
  };
  u16*    Xbf     = (u16*)alloc((size_t)4096 * 1024 * 2);
  u16*    WqkvT   = (u16*)alloc((size_t)3072 * 1024 * 2);
  u16*    caWinT  = (u16*)alloc((size_t)3072 * 1024 * 2);
  u16*    mcWinT  = (u16*)alloc((size_t)3072 * 1024 * 2);
  u16*    caWoutT = (u16*)alloc((size_t)1024 * 1024 * 2);
  u16*    mcWoutT = (u16*)alloc((size_t)1024 * 1024 * 2);
  u16*    WoT     = (u16*)alloc((size_t)1024 * 1024 * 2);
  float*  bqkv    = (float*)alloc(3072 * 4);
  float*  modb    = (float*)alloc((size_t)64 * 1024 * 4);
  u16*    big0    = (u16*)alloc((size_t)4096 * 3072 * 2);  // CAqkv -> QKVm -> MCqkv
  u16*    actx    = (u16*)alloc((size_t)4096 * 1024 * 2);
  u16*    ctxm    = (u16*)alloc((size_t)4096 * 1024 * 2);
  u16*    ctx1    = (u16*)alloc((size_t)4096 * 1024 * 2);
  u16*    Opart   = (u16*)alloc((size_t)4 * 16 * 1024 * 256 * 2);  // 32 MB
  float2* Ml      = (float2*)alloc((size_t)4 * 16 * 1024 * 8);     // 512 KB
  u16*    mctx    = ctxm;  // alias: ctxm dead after causal blend gemm
  u16*    ctx2    = actx;  // alias: actx dead after causal blend gemm

  // ---- prep (5 launches)
  cast_bf16_kernel<<<4096, 256, 0, stream>>>(X, Xbf);
  {
    TBatch b6;
    b6.src[0] = Wq;     b6.dst[0] = WqkvT;
    b6.src[1] = Wk;     b6.dst[1] = WqkvT + (size_t)1024 * 1024;
    b6.src[2] = Wv;     b6.dst[2] = WqkvT + (size_t)2048 * 1024;
    b6.src[3] = caWout; b6.dst[3] = caWoutT;
    b6.src[4] = mcWout; b6.dst[4] = mcWoutT;
    b6.src[5] = Wo;     b6.dst[5] = WoT;
    transpose_cast_batch<<<dim3(32, 32, 6), dim3(32, 8), 0, stream>>>(b6, 1024, 1024);
    TBatch b2;
    b2.src[0] = caWin;  b2.dst[0] = caWinT;
    b2.src[1] = mcWin;  b2.dst[1] = mcWinT;
    b2.src[2] = b2.src[3] = b2.src[4] = b2.src[5] = nullptr;
    b2.dst[2] = b2.dst[3] = b2.dst[4] = b2.dst[5] = nullptr;
    transpose_cast_batch<<<dim3(96, 32, 2), dim3(32, 8), 0, stream>>>(b2, 1024, 3072);
  }
  pack_bias3<<<12, 256, 0, stream>>>(bq, bk, bv, bqkv);
  mod_kernel<<<4096, 256, 0, stream>>>(X, cgW, cgb, cons, amW, amb, modb);

  // ---- causal branch: in-proj -> split flash -> merge
  gemm_bt<0, 0, 128><<<dim3(24, 32), 256, 0, stream>>>(Xbf, caWinT, cabin, nullptr, 0.f, 0.f,
                                                       big0, 4096, 3072, 1024);
  flash_attn<256, 32, 0, 4><<<dim3(16, 16, 4), 256, 0, stream>>>(big0, nullptr, Opart, Ml,
                                                                 1.f / 16.f, 4);
  flash_merge<4><<<2048, 256, 0, stream>>>(Opart, Ml, actx, 4);
  // ---- main QKV + gated attention
  gemm_bt<0, 0, 128><<<dim3(24, 32), 256, 0, stream>>>(Xbf, WqkvT, bqkv, nullptr, 0.f, 0.f,
                                                       big0, 4096, 3072, 1024);
  flash_attn<64, 64, 1, 1><<<dim3(16, 64), 256, 0, stream>>>(big0, modb, ctxm, nullptr, 1.f, 16);
  // ctx1 = 0.3*ctxm + 0.7*(actx@caWout + cabout)
  gemm_bt<0, 1, 64><<<dim3(16, 32), 256, 0, stream>>>(actx, caWoutT, cabout, ctxm, 0.7f, 0.3f,
                                                      ctx1, 4096, 1024, 1024);
  // ---- meta branch: in-proj -> split flash -> merge
  gemm_bt<0, 0, 128><<<dim3(24, 32), 256, 0, stream>>>(ctx1, mcWinT, mcbin, nullptr, 0.f, 0.f,
                                                       big0, 4096, 3072, 1024);
  flash_attn<256, 32, 0, 4><<<dim3(16, 16, 4), 256, 0, stream>>>(big0, nullptr, Opart, Ml,
                                                                 1.f / 16.f, 4);
  flash_merge<4><<<2048, 256, 0, stream>>>(Opart, Ml, mctx, 4);
  // ctx2 = 0.85*ctx1 + 0.15*(mctx@mcWout + mcbout)
  gemm_bt<0, 1, 64><<<dim3(16, 32), 256, 0, stream>>>(mctx, mcWoutT, mcbout, ctx1, 0.15f, 0.85f,
                                                      ctx2, 4096, 1024, 1024);
  // out = ctx2@Wo + bo (fp32)
  gemm_bt<1, 0, 64><<<dim3(16, 32), 256, 0, stream>>>(ctx2, WoT, bo, nullptr, 0.f, 0.f,
                                                      d_out, 4096, 1024, 1024);
}

// Round 3
// 536.523 us; speedup vs baseline: 1.0809x; 1.0807x over previous
//
#include <hip/hip_runtime.h>
#include <stdint.h>

typedef unsigned short u16;
typedef __attribute__((ext_vector_type(8))) short short8;   // 8 x bf16 (4 VGPRs)
typedef __attribute__((ext_vector_type(4))) float f32x4;    // MFMA accumulator

#define MFMA16(a,b,c) __builtin_amdgcn_mfma_f32_16x16x32_bf16((a),(b),(c),0,0,0)

__device__ __forceinline__ u16 f2bf(float f) {
  union { float f; uint32_t u; } v; v.f = f;
  uint32_t r = v.u + 0x7FFFu + ((v.u >> 16) & 1u);   // RNE
  return (u16)(r >> 16);
}
__device__ __forceinline__ float bf2f(uint32_t u) {
  union { uint32_t i; float f; } v; v.i = u << 16; return v.f;
}
// async global->LDS, 16B per lane; LDS dest = wave-uniform base + lane*16
__device__ __forceinline__ void async_copy16(void* lds, const void* g) {
  __builtin_amdgcn_global_load_lds(
      (const __attribute__((address_space(1))) uint32_t*)g,
      (__attribute__((address_space(3))) uint32_t*)lds, 16, 0, 0);
}

// in-register 8x8 u16 transpose across 8 lanes (lane8 = lane&7), 4 u32 regs
__device__ __forceinline__ void transpose8x8(uint32_t r[4], int lane8) {
  uint32_t a0, a1, a2, a3;
  a0 = __shfl_xor(r[0], 4); a1 = __shfl_xor(r[1], 4);
  a2 = __shfl_xor(r[2], 4); a3 = __shfl_xor(r[3], 4);
  if (lane8 & 4) { r[0] = a2; r[1] = a3; } else { r[2] = a0; r[3] = a1; }
  a0 = __shfl_xor(r[0], 2); a1 = __shfl_xor(r[1], 2);
  a2 = __shfl_xor(r[2], 2); a3 = __shfl_xor(r[3], 2);
  if (lane8 & 2) { r[0] = a1; r[2] = a3; } else { r[1] = a0; r[3] = a2; }
  a0 = __shfl_xor(r[0], 1); a1 = __shfl_xor(r[1], 1);
  a2 = __shfl_xor(r[2], 1); a3 = __shfl_xor(r[3], 1);
  uint32_t sel = (lane8 & 1) ? 0x03020706u : 0x05040100u;
  r[0] = __builtin_amdgcn_perm(a0, r[0], sel);
  r[1] = __builtin_amdgcn_perm(a1, r[1], sel);
  r[2] = __builtin_amdgcn_perm(a2, r[2], sel);
  r[3] = __builtin_amdgcn_perm(a3, r[3], sel);
}

// ---------------------------------------------------------------------------
// fused: Xbf = bf16(X);  mod[b*16+h][s] = sigmoid(X@cgW + cgb + cons@amW + amb)/8
__global__ __launch_bounds__(256) void castmod_kernel(
    const float* __restrict__ X, u16* __restrict__ Xbf,
    const float* __restrict__ cgW, const float* __restrict__ cgb,
    const float* __restrict__ cons, const float* __restrict__ amW,
    const float* __restrict__ amb, float* __restrict__ modp) {
  __shared__ float xs[1024];
  __shared__ float part[16][16];
  __shared__ float am[16];
  int row = blockIdx.x, t = threadIdx.x;
  {
    float4 v = ((const float4*)(X + (size_t)row * 1024))[t];
    xs[t * 4 + 0] = v.x; xs[t * 4 + 1] = v.y; xs[t * 4 + 2] = v.z; xs[t * 4 + 3] = v.w;
    uint2 o;
    o.x = (uint32_t)f2bf(v.x) | ((uint32_t)f2bf(v.y) << 16);
    o.y = (uint32_t)f2bf(v.z) | ((uint32_t)f2bf(v.w) << 16);
    ((uint2*)Xbf)[(size_t)row * 256 + t] = o;
  }
  if (t < 16) {
    float a = amb[t];
#pragma unroll
    for (int i = 0; i < 16; i++) a += cons[i] * amW[i * 16 + t];
    am[t] = a;
  }
  __syncthreads();
  int h = t & 15, ch = t >> 4;
  float p = 0.f;
#pragma unroll 8
  for (int k = ch * 64; k < ch * 64 + 64; k++) p += xs[k] * cgW[k * 16 + h];
  part[ch][h] = p;
  __syncthreads();
  if (t < 16) {
    float s = cgb[t] + am[t];
#pragma unroll
    for (int c = 0; c < 16; c++) s += part[c][t];
    int b = row >> 10, si = row & 1023;
    modp[((size_t)(b * 16 + t)) * 1024 + si] = 0.125f / (1.f + __expf(-s));
  }
}

// batched transpose+cast: src fp32 [rows, cols] -> dst bf16 [cols, rows]
struct TBatch { const float* src[6]; u16* dst[6]; };
__global__ __launch_bounds__(256) void transpose_cast_batch(
    TBatch p, int rows, int cols) {
  __shared__ float tile[32][33];
  const float* __restrict__ in = p.src[blockIdx.z];
  u16* __restrict__ out = p.dst[blockIdx.z];
  int c0 = blockIdx.x * 32, r0 = blockIdx.y * 32;
  int tx = threadIdx.x, ty = threadIdx.y;   // (32,8)
#pragma unroll
  for (int j = 0; j < 4; j++)
    tile[ty + j * 8][tx] = in[(size_t)(r0 + ty + j * 8) * cols + c0 + tx];
  __syncthreads();
#pragma unroll
  for (int j = 0; j < 4; j++)
    out[(size_t)(c0 + ty + j * 8) * rows + r0 + tx] = f2bf(tile[tx][ty + j * 8]);
}

__global__ void pack_bias3(const float* __restrict__ a, const float* __restrict__ b,
                           const float* __restrict__ c, float* __restrict__ o) {
  int i = blockIdx.x * 256 + threadIdx.x;  // 3072
  o[i] = (i < 1024) ? a[i] : (i < 2048 ? b[i - 1024] : c[i - 2048]);
}

// ---------------------------------------------------------------------------
// bf16 GEMM, BK=64: C[M,N] = A[M,K] @ Bt[N,K]^T (+bias, optional blend)
// 128xBN tile, 4 waves. LDS rows are 64 u16 (all-bank alias) -> XOR-granule
// swizzle applied on the GLOBAL side of async staging; reads un-swizzle.
template <int OUT_F32, int HAS_EXTRA, int BN>
__global__ __launch_bounds__(256, 3) void gemm_bt(
    const u16* __restrict__ A, const u16* __restrict__ Bt,
    const float* __restrict__ bias, const u16* __restrict__ extra,
    float alpha, float beta, void* __restrict__ Cout, int M, int N, int K) {
  constexpr int NJ = BN / 32;   // j-tiles per wave
  __shared__ u16 As[128 * 64];
  __shared__ u16 Bs[BN * 64];
  const int t = threadIdx.x;
  const int w = t >> 6, l = t & 63, lm = l & 15, lg = l >> 4;
  const int wm = w & 1, wn = w >> 1;
  const int m0 = blockIdx.y * 128, n0 = blockIdx.x * BN;
  const int rl = l >> 3, gsrc8 = ((l & 7) ^ (rl & 7)) * 8;  // row&7 == rl&7 (base%8==0)
  const f32x4 fzero = {0.f, 0.f, 0.f, 0.f};
  f32x4 acc[4][NJ];
#pragma unroll
  for (int i = 0; i < 4; i++)
#pragma unroll
    for (int j = 0; j < NJ; j++) acc[i][j] = fzero;

  for (int kt = 0; kt < K; kt += 64) {
    __syncthreads();
#pragma unroll
    for (int c = 0; c < 4; c++) {       // A: 128 rows x 64 cols
      int rb = c * 32 + w * 8;
      async_copy16(&As[rb * 64], A + (size_t)(m0 + rb + rl) * K + kt + gsrc8);
    }
#pragma unroll
    for (int c = 0; c < BN / 32; c++) { // B: BN rows x 64 cols
      int rb = c * 32 + w * 8;
      async_copy16(&Bs[rb * 64], Bt + (size_t)(n0 + rb + rl) * K + kt + gsrc8);
    }
    __syncthreads();  // drains vmcnt for global_load_lds
#pragma unroll
    for (int kk = 0; kk < 2; kk++) {
      short8 af[4], bf[NJ];
      const int gph = ((kk * 4 + lg) ^ (lm & 7)) * 8;
#pragma unroll
      for (int i = 0; i < 4; i++)
        af[i] = *(const short8*)&As[(wm * 64 + i * 16 + lm) * 64 + gph];
#pragma unroll
      for (int j = 0; j < NJ; j++)
        bf[j] = *(const short8*)&Bs[(wn * (BN / 2) + j * 16 + lm) * 64 + gph];
#pragma unroll
      for (int i = 0; i < 4; i++)
#pragma unroll
        for (int j = 0; j < NJ; j++) acc[i][j] = MFMA16(af[i], bf[j], acc[i][j]);
    }
  }
  // epilogue: C-layout row=(lg*4+r), col=lm within each 16x16 tile
#pragma unroll
  for (int i = 0; i < 4; i++) {
    int row0 = m0 + wm * 64 + i * 16 + lg * 4;
#pragma unroll
    for (int j = 0; j < NJ; j++) {
      int col = n0 + wn * (BN / 2) + j * 16 + lm;
      float bc = bias[col];
#pragma unroll
      for (int r = 0; r < 4; r++) {
        size_t idx = (size_t)(row0 + r) * N + col;
        float v = acc[i][j][r] + bc;
        if constexpr (HAS_EXTRA) v = alpha * v + beta * bf2f(extra[idx]);
        if constexpr (OUT_F32) ((float*)Cout)[idx] = v;
        else ((u16*)Cout)[idx] = f2bf(v);
      }
    }
  }
}

// ---------------------------------------------------------------------------
// MFMA flash attention, no mask, S=1024. qkv: bf16 [B*S, 3072], q|k|v at col
// 0|1024|2048, head h at +h*HD. 4 waves, BQ=64 (16 q-rows/wave). 1-D grid of
// 1024 blocks, XCD-grouped so all 16 q-blocks of a (bh[,z]) share one XCD.
// SPLIT>1: kv slice z, unnormalized O (bf16) + (m,l) partials for merge pass.
template <int HD, int BKV, int USE_MOD, int SPLIT>
__global__ __launch_bounds__(256, 3) void flash_attn(
    const u16* __restrict__ qkv, const float* __restrict__ modp,
    u16* __restrict__ outp, float2* __restrict__ ml, float scale, int NH) {
  constexpr int S = 1024, W3 = 3072, Hh = 1024;
  constexpr int NKD = HD / 32;     // d-steps for QK^T
  constexpr int NT  = BKV / 16;    // col-subtiles of S
  constexpr int ND  = HD / 16;     // col-subtiles of O
  constexpr int NKP = BKV / 32;    // k-steps for PV
  constexpr int KC  = (BKV * HD) / 2048;  // V staging rounds
  constexpr int VSTR = BKV + 8;    // stride_dw=(BKV+8)/2: 128->68, 32->20 (conflict-free phases)
  constexpr int PSTR = BKV + 8;
  constexpr int KVLEN = S / SPLIT;
  constexpr int OPR = HD / 8;      // d-octets per V row
  constexpr int KVR = 2048 / HD;   // kv rows per V staging round
  constexpr int GPR = HD / 8;      // K granules per row
  constexpr int RPW = 64 / GPR;    // K rows per wave per async round

  __shared__ u16 Ks[BKV * HD];     // XOR-swizzled granules (swizzle on global side)
  __shared__ u16 Vt[HD * VSTR];    // V transposed: Vt[d][k]
  __shared__ u16 Ps[64 * PSTR];    // P in A-operand layout [q][k]

  const int t = threadIdx.x, w = t >> 6, l = t & 63, lm = l & 15, lg = l >> 4;
  // XCD-grouping decode: bids congruent mod 8 (same XCD) share one sid
  const int bid = blockIdx.x;
  const int rest = bid >> 3;
  const int q0 = (rest & 15) * 64;
  const int sid = (bid & 7) + 8 * (rest >> 4);          // 0..63
  const int bh = (SPLIT > 1) ? (sid & 15) : sid;
  const int z  = (SPLIT > 1) ? (sid >> 4) : 0;
  const int b = bh / NH, h = bh % NH;
  const size_t rowbase = (size_t)b * S;

  // V staging geometry: octet oc, lane-in-octet kvo
  const int oc = t >> 3, kvo = t & 7;
  const int sd0 = (oc % OPR) * 8;        // d octet base
  const int skvg = (oc / OPR) * 8;       // kv group base within round

  // Q fragments in registers (A-layout: row=lm, k=lg*8+j within 32-chunk)
  short8 qf[NKD];
  {
    const u16* qp = qkv + (rowbase + q0 + w * 16 + lm) * W3 + h * HD + lg * 8;
#pragma unroll
    for (int d = 0; d < NKD; d++) qf[d] = *(const short8*)(qp + d * 32);
  }
  float rs[4];
#pragma unroll
  for (int r = 0; r < 4; r++) {
    if constexpr (USE_MOD)
      rs[r] = modp[(size_t)bh * S + q0 + w * 16 + lg * 4 + r];
    else
      rs[r] = scale;
  }

  float m_i[4], l_i[4];
#pragma unroll
  for (int r = 0; r < 4; r++) { m_i[r] = -1e30f; l_i[r] = 0.f; }
  const f32x4 fzero = {0.f, 0.f, 0.f, 0.f};
  f32x4 oacc[ND];
#pragma unroll
  for (int d = 0; d < ND; d++) oacc[d] = fzero;

  for (int kb = z * KVLEN; kb < z * KVLEN + KVLEN; kb += BKV) {
    __syncthreads();  // all waves done reading Ks/Vt from previous tile
    // ---- stage K tile: async DMA, XOR-granule swizzle on the global side
#pragma unroll
    for (int c = 0; c < BKV / (4 * RPW); c++) {
      int rb = c * (4 * RPW) + w * RPW;
      int row = rb + l / GPR;
      int gsrc = ((l % GPR) ^ (row & 7)) * 8;
      async_copy16(&Ks[rb * HD],
                   qkv + (rowbase + kb + row) * W3 + Hh + h * HD + gsrc);
    }
    // ---- stage V transposed via in-register 8x8 butterfly (b128 writes)
#pragma unroll
    for (int c = 0; c < KC; c++) {
      int kv = c * KVR + skvg + kvo;
      union { short8 s; uint32_t u[4]; } vv, vo;
      vv.s = *(const short8*)(qkv + (rowbase + kb + kv) * W3 + 2 * Hh + h * HD + sd0);
      uint32_t r[4] = {vv.u[0], vv.u[1], vv.u[2], vv.u[3]};
      transpose8x8(r, kvo);
      vo.u[0] = r[0]; vo.u[1] = r[1]; vo.u[2] = r[2]; vo.u[3] = r[3];
      *(short8*)&Vt[(sd0 + kvo) * VSTR + c * KVR + skvg] = vo.s;
    }
    __syncthreads();

    // ---- S = Q K^T  (C-layout: row=q=lg*4+r, col=k=n*16+lm)
    f32x4 sacc[NT];
#pragma unroll
    for (int n = 0; n < NT; n++) sacc[n] = fzero;
#pragma unroll
    for (int n = 0; n < NT; n++) {
      int krow = n * 16 + lm;
#pragma unroll
      for (int d = 0; d < NKD; d++) {
        int g = d * 4 + lg;
        short8 kf = *(const short8*)&Ks[krow * HD + ((g ^ (krow & 7)) * 8)];
        sacc[n] = MFMA16(qf[d], kf, sacc[n]);
      }
    }
    // ---- online softmax (row stats across 16-lane col group), in-place
    float alpha_[4];
#pragma unroll
    for (int r = 0; r < 4; r++) {
      float mx = -1e30f;
#pragma unroll
      for (int n = 0; n < NT; n++) {
        float v = sacc[n][r] * rs[r]; sacc[n][r] = v; mx = fmaxf(mx, v);
      }
#pragma unroll
      for (int s = 8; s >= 1; s >>= 1) mx = fmaxf(mx, __shfl_xor(mx, s));
      float mnew = fmaxf(m_i[r], mx);
      alpha_[r] = __expf(m_i[r] - mnew);
      float sum = 0.f;
#pragma unroll
      for (int n = 0; n < NT; n++) {
        float e = __expf(sacc[n][r] - mnew); sacc[n][r] = e; sum += e;
      }
#pragma unroll
      for (int s = 8; s >= 1; s >>= 1) sum += __shfl_xor(sum, s);
      l_i[r] = l_i[r] * alpha_[r] + sum;
      m_i[r] = mnew;
    }
#pragma unroll
    for (int d = 0; d < ND; d++)
#pragma unroll
      for (int r = 0; r < 4; r++) oacc[d][r] *= alpha_[r];
    // ---- P -> LDS (bf16), same-wave rows only: no barrier needed
#pragma unroll
    for (int n = 0; n < NT; n++)
#pragma unroll
      for (int r = 0; r < 4; r++)
        Ps[(w * 16 + lg * 4 + r) * PSTR + n * 16 + lm] = f2bf(sacc[n][r]);
    // ---- O += P V
#pragma unroll
    for (int ks = 0; ks < NKP; ks++) {
      short8 pf = *(const short8*)&Ps[(w * 16 + lm) * PSTR + ks * 32 + lg * 8];
#pragma unroll
      for (int d = 0; d < ND; d++) {
        short8 vf = *(const short8*)&Vt[(d * 16 + lm) * VSTR + ks * 32 + lg * 8];
        oacc[d] = MFMA16(pf, vf, oacc[d]);
      }
    }
  }
  // ---- epilogue
  if constexpr (SPLIT > 1) {
    const size_t obase = ((size_t)(z * 16 + bh)) << 10;
#pragma unroll
    for (int d = 0; d < ND; d++) {
      int col = d * 16 + lm;
#pragma unroll
      for (int r = 0; r < 4; r++) {
        int row = q0 + w * 16 + lg * 4 + r;
        outp[(obase + row) * HD + col] = f2bf(oacc[d][r]);
      }
    }
    if (lm == 0) {
#pragma unroll
      for (int r = 0; r < 4; r++) {
        int row = q0 + w * 16 + lg * 4 + r;
        ml[obase + row] = make_float2(m_i[r], l_i[r]);
      }
    }
  } else {
#pragma unroll
    for (int d = 0; d < ND; d++) {
      int col = h * HD + d * 16 + lm;
#pragma unroll
      for (int r = 0; r < 4; r++) {
        int row = q0 + w * 16 + lg * 4 + r;
        outp[(rowbase + row) * 1024 + col] = f2bf(oacc[d][r] / l_i[r]);
      }
    }
  }
}

// ---------------------------------------------------------------------------
// merge SPLIT kv-partials (HD=256 branches): out = sum_s a_s O_s / sum_s a_s l_s
template <int SPLIT>
__global__ __launch_bounds__(256) void flash_merge(
    const u16* __restrict__ Opart, const float2* __restrict__ ml,
    u16* __restrict__ outp, int NH) {
  constexpr int NBH = 16;
  const int t = threadIdx.x;
  const int r8 = t >> 5, cg = t & 31;          // 8 rows x 32 col-groups
  const int R = blockIdx.x * 8 + r8;           // 0..16383
  const int bh = R >> 10, srow = R & 1023;
  const int b = bh / NH, h = bh % NH;
  float2 msl[SPLIT];
  float M = -1e30f;
#pragma unroll
  for (int s = 0; s < SPLIT; s++) {
    msl[s] = ml[(((size_t)(s * NBH + bh)) << 10) + srow];
    M = fmaxf(M, msl[s].x);
  }
  float L = 0.f, wgt[SPLIT];
#pragma unroll
  for (int s = 0; s < SPLIT; s++) { wgt[s] = __expf(msl[s].x - M); L += wgt[s] * msl[s].y; }
  const float inv = 1.f / L;
  float acc[8] = {0.f, 0.f, 0.f, 0.f, 0.f, 0.f, 0.f, 0.f};
#pragma unroll
  for (int s = 0; s < SPLIT; s++) {
    const u16* p = Opart + ((((size_t)(s * NBH + bh)) << 10) + srow) * 256 + cg * 8;
    uint4 v = *(const uint4*)p;
    float ws = wgt[s];
    acc[0] += ws * bf2f(v.x & 0xffffu); acc[1] += ws * bf2f(v.x >> 16);
    acc[2] += ws * bf2f(v.y & 0xffffu); acc[3] += ws * bf2f(v.y >> 16);
    acc[4] += ws * bf2f(v.z & 0xffffu); acc[5] += ws * bf2f(v.z >> 16);
    acc[6] += ws * bf2f(v.w & 0xffffu); acc[7] += ws * bf2f(v.w >> 16);
  }
  u16 o[8];
#pragma unroll
  for (int j = 0; j < 8; j++) o[j] = f2bf(acc[j] * inv);
  *(uint4*)&outp[((size_t)(b * 1024 + srow)) * 1024 + h * 256 + cg * 8] = *(const uint4*)o;
}

// ---------------------------------------------------------------------------
extern "C" void kernel_launch(void* const* d_in, const int* in_sizes, int n_in,
                              void* d_out, int out_size, void* d_ws, size_t ws_size,
                              hipStream_t stream) {
  (void)in_sizes; (void)n_in; (void)out_size; (void)ws_size;
  const float* X      = (const float*)d_in[0];
  const float* cons   = (const float*)d_in[1];
  const float* Wq     = (const float*)d_in[2];  const float* bq     = (const float*)d_in[3];
  const float* Wk     = (const float*)d_in[4];  const float* bk     = (const float*)d_in[5];
  const float* Wv     = (const float*)d_in[6];  const float* bv     = (const float*)d_in[7];
  const float* cgW    = (const float*)d_in[8];  const float* cgb    = (const float*)d_in[9];
  const float* amW    = (const float*)d_in[10]; const float* amb    = (const float*)d_in[11];
  const float* caWin  = (const float*)d_in[12]; const float* cabin  = (const float*)d_in[13];
  const float* caWout = (const float*)d_in[14]; const float* cabout = (const float*)d_in[15];
  const float* mcWin  = (const float*)d_in[16]; const float* mcbin  = (const float*)d_in[17];
  const float* mcWout = (const float*)d_in[18]; const float* mcbout = (const float*)d_in[19];
  const float* Wo     = (const float*)d_in[20]; const float* bo     = (const float*)d_in[21];

  char* ws = (char*)d_ws;
  size_t off = 0;
  auto alloc = [&](size_t bytes) -> void* {
    void* p = ws + off; off += (bytes + 255) & ~(size_t)255; return p;
  };
  u16*    Xbf     = (u16*)alloc((size_t)4096 * 1024 * 2);
  u16*    WqkvT   = (u16*)alloc((size_t)3072 * 1024 * 2);
  u16*    caWinT  = (u16*)alloc((size_t)3072 * 1024 * 2);
  u16*    mcWinT  = (u16*)alloc((size_t)3072 * 1024 * 2);
  u16*    caWoutT = (u16*)alloc((size_t)1024 * 1024 * 2);
  u16*    mcWoutT = (u16*)alloc((size_t)1024 * 1024 * 2);
  u16*    WoT     = (u16*)alloc((size_t)1024 * 1024 * 2);
  float*  bqkv    = (float*)alloc(3072 * 4);
  float*  modb    = (float*)alloc((size_t)64 * 1024 * 4);
  u16*    big0    = (u16*)alloc((size_t)4096 * 3072 * 2);  // CAqkv -> QKVm -> MCqkv
  u16*    actx    = (u16*)alloc((size_t)4096 * 1024 * 2);
  u16*    ctxm    = (u16*)alloc((size_t)4096 * 1024 * 2);
  u16*    ctx1    = (u16*)alloc((size_t)4096 * 1024 * 2);
  u16*    Opart   = (u16*)alloc((size_t)4 * 16 * 1024 * 256 * 2);  // 32 MB
  float2* Ml      = (float2*)alloc((size_t)4 * 16 * 1024 * 8);     // 512 KB
  u16*    mctx    = ctxm;  // alias: ctxm dead after causal blend gemm
  u16*    ctx2    = actx;  // alias: actx dead after causal blend gemm

  // ---- prep (4 launches)
  castmod_kernel<<<4096, 256, 0, stream>>>(X, Xbf, cgW, cgb, cons, amW, amb, modb);
  {
    TBatch b6;
    b6.src[0] = Wq;     b6.dst[0] = WqkvT;
    b6.src[1] = Wk;     b6.dst[1] = WqkvT + (size_t)1024 * 1024;
    b6.src[2] = Wv;     b6.dst[2] = WqkvT + (size_t)2048 * 1024;
    b6.src[3] = caWout; b6.dst[3] = caWoutT;
    b6.src[4] = mcWout; b6.dst[4] = mcWoutT;
    b6.src[5] = Wo;     b6.dst[5] = WoT;
    transpose_cast_batch<<<dim3(32, 32, 6), dim3(32, 8), 0, stream>>>(b6, 1024, 1024);
    TBatch b2;
    b2.src[0] = caWin;  b2.dst[0] = caWinT;
    b2.src[1] = mcWin;  b2.dst[1] = mcWinT;
    b2.src[2] = b2.src[3] = b2.src[4] = b2.src[5] = nullptr;
    b2.dst[2] = b2.dst[3] = b2.dst[4] = b2.dst[5] = nullptr;
    transpose_cast_batch<<<dim3(96, 32, 2), dim3(32, 8), 0, stream>>>(b2, 1024, 3072);
  }
  pack_bias3<<<12, 256, 0, stream>>>(bq, bk, bv, bqkv);

  // ---- causal branch: in-proj -> split flash -> merge
  gemm_bt<0, 0, 128><<<dim3(24, 32), 256, 0, stream>>>(Xbf, caWinT, cabin, nullptr, 0.f, 0.f,
                                                       big0, 4096, 3072, 1024);
  flash_attn<256, 32, 0, 4><<<1024, 256, 0, stream>>>(big0, nullptr, Opart, Ml, 1.f / 16.f, 4);
  flash_merge<4><<<2048, 256, 0, stream>>>(Opart, Ml, actx, 4);
  // ---- main QKV + gated attention (BKV=128)
  gemm_bt<0, 0, 128><<<dim3(24, 32), 256, 0, stream>>>(Xbf, WqkvT, bqkv, nullptr, 0.f, 0.f,
                                                       big0, 4096, 3072, 1024);
  flash_attn<64, 128, 1, 1><<<1024, 256, 0, stream>>>(big0, modb, ctxm, nullptr, 1.f, 16);
  // ctx1 = 0.3*ctxm + 0.7*(actx@caWout + cabout)
  gemm_bt<0, 1, 64><<<dim3(16, 32), 256, 0, stream>>>(actx, caWoutT, cabout, ctxm, 0.7f, 0.3f,
                                                      ctx1, 4096, 1024, 1024);
  // ---- meta branch: in-proj -> split flash -> merge
  gemm_bt<0, 0, 128><<<dim3(24, 32), 256, 0, stream>>>(ctx1, mcWinT, mcbin, nullptr, 0.f, 0.f,
                                                       big0, 4096, 3072, 1024);
  flash_attn<256, 32, 0, 4><<<1024, 256, 0, stream>>>(big0, nullptr, Opart, Ml, 1.f / 16.f, 4);
  flash_merge<4><<<2048, 256, 0, stream>>>(Opart, Ml, mctx, 4);
  // ctx2 = 0.85*ctx1 + 0.15*(mctx@mcWout + mcbout)
  gemm_bt<0, 1, 64><<<dim3(16, 32), 256, 0, stream>>>(mctx, mcWoutT, mcbout, ctx1, 0.15f, 0.85f,
                                                      ctx2, 4096, 1024, 1024);
  // out = ctx2@Wo + bo (fp32)
  gemm_bt<1, 0, 64><<<dim3(16, 32), 256, 0, stream>>>(ctx2, WoT, bo, nullptr, 0.f, 0.f,
                                                      d_out, 4096, 1024, 1024);
}

// Round 4
// 482.401 us; speedup vs baseline: 1.2021x; 1.1122x over previous
//
#include <hip/hip_runtime.h>
#include <stdint.h>

typedef unsigned short u16;
typedef __attribute__((ext_vector_type(8))) short short8;   // 8 x bf16 (4 VGPRs)
typedef __attribute__((ext_vector_type(4))) float f32x4;    // MFMA accumulator

#define MFMA16(a,b,c) __builtin_amdgcn_mfma_f32_16x16x32_bf16((a),(b),(c),0,0,0)

__device__ __forceinline__ u16 f2bf(float f) {
  union { float f; uint32_t u; } v; v.f = f;
  uint32_t r = v.u + 0x7FFFu + ((v.u >> 16) & 1u);   // RNE
  return (u16)(r >> 16);
}
__device__ __forceinline__ float bf2f(uint32_t u) {
  union { uint32_t i; float f; } v; v.i = u << 16; return v.f;
}
// async global->LDS, 16B per lane; LDS dest = wave-uniform base + lane*16
__device__ __forceinline__ void async_copy16(void* lds, const void* g) {
  __builtin_amdgcn_global_load_lds(
      (const __attribute__((address_space(1))) uint32_t*)g,
      (__attribute__((address_space(3))) uint32_t*)lds, 16, 0, 0);
}

// in-register 8x8 u16 transpose across 8 lanes (lane8 = lane&7), 4 u32 regs
__device__ __forceinline__ void transpose8x8(uint32_t r[4], int lane8) {
  uint32_t a0, a1, a2, a3;
  a0 = __shfl_xor(r[0], 4); a1 = __shfl_xor(r[1], 4);
  a2 = __shfl_xor(r[2], 4); a3 = __shfl_xor(r[3], 4);
  if (lane8 & 4) { r[0] = a2; r[1] = a3; } else { r[2] = a0; r[3] = a1; }
  a0 = __shfl_xor(r[0], 2); a1 = __shfl_xor(r[1], 2);
  a2 = __shfl_xor(r[2], 2); a3 = __shfl_xor(r[3], 2);
  if (lane8 & 2) { r[0] = a1; r[2] = a3; } else { r[1] = a0; r[3] = a2; }
  a0 = __shfl_xor(r[0], 1); a1 = __shfl_xor(r[1], 1);
  a2 = __shfl_xor(r[2], 1); a3 = __shfl_xor(r[3], 1);
  uint32_t sel = (lane8 & 1) ? 0x03020706u : 0x05040100u;
  r[0] = __builtin_amdgcn_perm(a0, r[0], sel);
  r[1] = __builtin_amdgcn_perm(a1, r[1], sel);
  r[2] = __builtin_amdgcn_perm(a2, r[2], sel);
  r[3] = __builtin_amdgcn_perm(a3, r[3], sel);
}

// ---------------------------------------------------------------------------
// fused: Xbf = bf16(X);  mod[b*16+h][s] = sigmoid(X@cgW + cgb + cons@amW + amb)/8
__global__ __launch_bounds__(256) void castmod_kernel(
    const float* __restrict__ X, u16* __restrict__ Xbf,
    const float* __restrict__ cgW, const float* __restrict__ cgb,
    const float* __restrict__ cons, const float* __restrict__ amW,
    const float* __restrict__ amb, float* __restrict__ modp) {
  __shared__ float xs[1024];
  __shared__ float part[16][16];
  __shared__ float am[16];
  int row = blockIdx.x, t = threadIdx.x;
  {
    float4 v = ((const float4*)(X + (size_t)row * 1024))[t];
    xs[t * 4 + 0] = v.x; xs[t * 4 + 1] = v.y; xs[t * 4 + 2] = v.z; xs[t * 4 + 3] = v.w;
    uint2 o;
    o.x = (uint32_t)f2bf(v.x) | ((uint32_t)f2bf(v.y) << 16);
    o.y = (uint32_t)f2bf(v.z) | ((uint32_t)f2bf(v.w) << 16);
    ((uint2*)Xbf)[(size_t)row * 256 + t] = o;
  }
  if (t < 16) {
    float a = amb[t];
#pragma unroll
    for (int i = 0; i < 16; i++) a += cons[i] * amW[i * 16 + t];
    am[t] = a;
  }
  __syncthreads();
  int h = t & 15, ch = t >> 4;
  float p = 0.f;
#pragma unroll 8
  for (int k = ch * 64; k < ch * 64 + 64; k++) p += xs[k] * cgW[k * 16 + h];
  part[ch][h] = p;
  __syncthreads();
  if (t < 16) {
    float s = cgb[t] + am[t];
#pragma unroll
    for (int c = 0; c < 16; c++) s += part[c][t];
    int b = row >> 10, si = row & 1023;
    modp[((size_t)(b * 16 + t)) * 1024 + si] = 0.125f / (1.f + __expf(-s));
  }
}

// batched transpose+cast: src fp32 [rows, cols] -> dst bf16 [cols, rows]
struct TBatch { const float* src[6]; u16* dst[6]; };
__global__ __launch_bounds__(256) void transpose_cast_batch(
    TBatch p, int rows, int cols) {
  __shared__ float tile[32][33];
  const float* __restrict__ in = p.src[blockIdx.z];
  u16* __restrict__ out = p.dst[blockIdx.z];
  int c0 = blockIdx.x * 32, r0 = blockIdx.y * 32;
  int tx = threadIdx.x, ty = threadIdx.y;   // (32,8)
#pragma unroll
  for (int j = 0; j < 4; j++)
    tile[ty + j * 8][tx] = in[(size_t)(r0 + ty + j * 8) * cols + c0 + tx];
  __syncthreads();
#pragma unroll
  for (int j = 0; j < 4; j++)
    out[(size_t)(c0 + ty + j * 8) * rows + r0 + tx] = f2bf(tile[tx][ty + j * 8]);
}

__global__ void pack_bias3(const float* __restrict__ a, const float* __restrict__ b,
                           const float* __restrict__ c, float* __restrict__ o) {
  int i = blockIdx.x * 256 + threadIdx.x;  // 3072
  o[i] = (i < 1024) ? a[i] : (i < 2048 ? b[i - 1024] : c[i - 2048]);
}

__global__ void zero_f32(float* __restrict__ p) {
  p[blockIdx.x * 256 + threadIdx.x] = 0.f;
}

// ---------------------------------------------------------------------------
// bf16 GEMM, BK=64: C[M,N] = A[M,K] @ Bt[N,K]^T (+bias, optional blend)
// 128xBN tile, 4 waves. XOR-granule swizzle on the GLOBAL side of async
// staging; reads un-swizzle.
template <int OUT_F32, int HAS_EXTRA, int BN>
__global__ __launch_bounds__(256, 3) void gemm_bt(
    const u16* __restrict__ A, const u16* __restrict__ Bt,
    const float* __restrict__ bias, const u16* __restrict__ extra,
    float alpha, float beta, void* __restrict__ Cout, int M, int N, int K) {
  constexpr int NJ = BN / 32;   // j-tiles per wave
  __shared__ u16 As[128 * 64];
  __shared__ u16 Bs[BN * 64];
  const int t = threadIdx.x;
  const int w = t >> 6, l = t & 63, lm = l & 15, lg = l >> 4;
  const int wm = w & 1, wn = w >> 1;
  const int m0 = blockIdx.y * 128, n0 = blockIdx.x * BN;
  const int rl = l >> 3, gsrc8 = ((l & 7) ^ (rl & 7)) * 8;
  const f32x4 fzero = {0.f, 0.f, 0.f, 0.f};
  f32x4 acc[4][NJ];
#pragma unroll
  for (int i = 0; i < 4; i++)
#pragma unroll
    for (int j = 0; j < NJ; j++) acc[i][j] = fzero;

  for (int kt = 0; kt < K; kt += 64) {
    __syncthreads();
#pragma unroll
    for (int c = 0; c < 4; c++) {       // A: 128 rows x 64 cols
      int rb = c * 32 + w * 8;
      async_copy16(&As[rb * 64], A + (size_t)(m0 + rb + rl) * K + kt + gsrc8);
    }
#pragma unroll
    for (int c = 0; c < BN / 32; c++) { // B: BN rows x 64 cols
      int rb = c * 32 + w * 8;
      async_copy16(&Bs[rb * 64], Bt + (size_t)(n0 + rb + rl) * K + kt + gsrc8);
    }
    __syncthreads();
#pragma unroll
    for (int kk = 0; kk < 2; kk++) {
      short8 af[4], bf[NJ];
      const int gph = ((kk * 4 + lg) ^ (lm & 7)) * 8;
#pragma unroll
      for (int i = 0; i < 4; i++)
        af[i] = *(const short8*)&As[(wm * 64 + i * 16 + lm) * 64 + gph];
#pragma unroll
      for (int j = 0; j < NJ; j++)
        bf[j] = *(const short8*)&Bs[(wn * (BN / 2) + j * 16 + lm) * 64 + gph];
#pragma unroll
      for (int i = 0; i < 4; i++)
#pragma unroll
        for (int j = 0; j < NJ; j++) acc[i][j] = MFMA16(af[i], bf[j], acc[i][j]);
    }
  }
#pragma unroll
  for (int i = 0; i < 4; i++) {
    int row0 = m0 + wm * 64 + i * 16 + lg * 4;
#pragma unroll
    for (int j = 0; j < NJ; j++) {
      int col = n0 + wn * (BN / 2) + j * 16 + lm;
      float bc = bias[col];
#pragma unroll
      for (int r = 0; r < 4; r++) {
        size_t idx = (size_t)(row0 + r) * N + col;
        float v = acc[i][j][r] + bc;
        if constexpr (HAS_EXTRA) v = alpha * v + beta * bf2f(extra[idx]);
        if constexpr (OUT_F32) ((float*)Cout)[idx] = v;
        else ((u16*)Cout)[idx] = f2bf(v);
      }
    }
  }
}

// ---------------------------------------------------------------------------
// in-proj V^T variant: C[4096][1024] = A @ Bt^T + bias, stored transposed per
// head: Vtb[z=(row>>10)*4+(col>>8)][d=col&255][q=row&1023]
__global__ __launch_bounds__(256, 3) void gemm_vt(
    const u16* __restrict__ A, const u16* __restrict__ Bt,
    const float* __restrict__ bias, u16* __restrict__ Vtb) {
  constexpr int K = 1024;
  __shared__ u16 As[128 * 64];
  __shared__ u16 Bs[128 * 64];
  const int t = threadIdx.x;
  const int w = t >> 6, l = t & 63, lm = l & 15, lg = l >> 4;
  const int wm = w & 1, wn = w >> 1;
  const int m0 = blockIdx.y * 128, n0 = blockIdx.x * 128;
  const int rl = l >> 3, gsrc8 = ((l & 7) ^ (rl & 7)) * 8;
  const f32x4 fzero = {0.f, 0.f, 0.f, 0.f};
  f32x4 acc[4][4];
#pragma unroll
  for (int i = 0; i < 4; i++)
#pragma unroll
    for (int j = 0; j < 4; j++) acc[i][j] = fzero;

  for (int kt = 0; kt < K; kt += 64) {
    __syncthreads();
#pragma unroll
    for (int c = 0; c < 4; c++) {
      int rb = c * 32 + w * 8;
      async_copy16(&As[rb * 64], A + (size_t)(m0 + rb + rl) * K + kt + gsrc8);
      async_copy16(&Bs[rb * 64], Bt + (size_t)(n0 + rb + rl) * K + kt + gsrc8);
    }
    __syncthreads();
#pragma unroll
    for (int kk = 0; kk < 2; kk++) {
      short8 af[4], bf[4];
      const int gph = ((kk * 4 + lg) ^ (lm & 7)) * 8;
#pragma unroll
      for (int i = 0; i < 4; i++)
        af[i] = *(const short8*)&As[(wm * 64 + i * 16 + lm) * 64 + gph];
#pragma unroll
      for (int j = 0; j < 4; j++)
        bf[j] = *(const short8*)&Bs[(wn * 64 + j * 16 + lm) * 64 + gph];
#pragma unroll
      for (int i = 0; i < 4; i++)
#pragma unroll
        for (int j = 0; j < 4; j++) acc[i][j] = MFMA16(af[i], bf[j], acc[i][j]);
    }
  }
#pragma unroll
  for (int i = 0; i < 4; i++) {
    int row0 = m0 + wm * 64 + i * 16 + lg * 4;
    int b = row0 >> 10, q0 = row0 & 1023;
#pragma unroll
    for (int j = 0; j < 4; j++) {
      int col = n0 + wn * 64 + j * 16 + lm;
      float bc = bias[col];
      int z = b * 4 + (col >> 8), d = col & 255;
      union { u16 pk[4]; uint2 v; } u;
#pragma unroll
      for (int r = 0; r < 4; r++) u.pk[r] = f2bf(acc[i][j][r] + bc);
      *(uint2*)&Vtb[((size_t)z * 256 + d) * 1024 + q0] = u.v;
    }
  }
}

// ---------------------------------------------------------------------------
// batched QK^T with exp epilogue + fused row-sum atomics (fixed-max softmax).
// z: b=z>>2, h=z&3. A=Q rows, B=K rows of qkv[B*S][3072], stride 3072, Kdim=256.
// P[z][q][kv] = exp(acc*scale) bf16;  lrow[z][q] += rowsum (pre-zeroed).
__global__ __launch_bounds__(256, 3) void gemm_qk_exp(
    const u16* __restrict__ qkv, u16* __restrict__ P, float* __restrict__ lrow,
    float scale) {
  constexpr int W3 = 3072;
  __shared__ u16 As[128 * 64];
  __shared__ u16 Bs[128 * 64];
  const int t = threadIdx.x;
  const int w = t >> 6, l = t & 63, lm = l & 15, lg = l >> 4;
  const int wm = w & 1, wn = w >> 1;
  const int z = blockIdx.z, b = z >> 2, h = z & 3;
  const int m0 = blockIdx.y * 128, n0 = blockIdx.x * 128;
  const u16* Abase = qkv + ((size_t)b << 10) * W3 + h * 256;          // Q
  const u16* Bbase = qkv + ((size_t)b << 10) * W3 + 1024 + h * 256;   // K
  const int rl = l >> 3, gsrc8 = ((l & 7) ^ (rl & 7)) * 8;
  const f32x4 fzero = {0.f, 0.f, 0.f, 0.f};
  f32x4 acc[4][4];
#pragma unroll
  for (int i = 0; i < 4; i++)
#pragma unroll
    for (int j = 0; j < 4; j++) acc[i][j] = fzero;

#pragma unroll
  for (int kt = 0; kt < 256; kt += 64) {
    __syncthreads();
#pragma unroll
    for (int c = 0; c < 4; c++) {
      int rb = c * 32 + w * 8;
      async_copy16(&As[rb * 64], Abase + (size_t)(m0 + rb + rl) * W3 + kt + gsrc8);
      async_copy16(&Bs[rb * 64], Bbase + (size_t)(n0 + rb + rl) * W3 + kt + gsrc8);
    }
    __syncthreads();
#pragma unroll
    for (int kk = 0; kk < 2; kk++) {
      short8 af[4], bf[4];
      const int gph = ((kk * 4 + lg) ^ (lm & 7)) * 8;
#pragma unroll
      for (int i = 0; i < 4; i++)
        af[i] = *(const short8*)&As[(wm * 64 + i * 16 + lm) * 64 + gph];
#pragma unroll
      for (int j = 0; j < 4; j++)
        bf[j] = *(const short8*)&Bs[(wn * 64 + j * 16 + lm) * 64 + gph];
#pragma unroll
      for (int i = 0; i < 4; i++)
#pragma unroll
        for (int j = 0; j < 4; j++) acc[i][j] = MFMA16(af[i], bf[j], acc[i][j]);
    }
  }
  // epilogue: P = exp(acc*scale), rowsum via lane-reduce + atomicAdd
  u16* Pz = P + ((size_t)z << 20);
#pragma unroll
  for (int i = 0; i < 4; i++) {
    int row0 = m0 + wm * 64 + i * 16 + lg * 4;
    float rsum[4] = {0.f, 0.f, 0.f, 0.f};
#pragma unroll
    for (int j = 0; j < 4; j++) {
      int col = n0 + wn * 64 + j * 16 + lm;
#pragma unroll
      for (int r = 0; r < 4; r++) {
        float p = __expf(acc[i][j][r] * scale);
        rsum[r] += p;
        Pz[(size_t)(row0 + r) * 1024 + col] = f2bf(p);
      }
    }
#pragma unroll
    for (int r = 0; r < 4; r++) {
      float s = rsum[r];
#pragma unroll
      for (int sh = 1; sh <= 8; sh <<= 1) s += __shfl_xor(s, sh);
      if (lm == 0) atomicAdd(&lrow[(z << 10) + row0 + r], s);
    }
  }
}

// ---------------------------------------------------------------------------
// batched PV: O[q][d] = (P[z] @ Vtb[z]^T) / l, stored into ctx[B*S][1024] at
// col h*256. A=P[z] (M=1024,K=1024,str 1024), Bt=Vtb[z] (256 rows,str 1024).
__global__ __launch_bounds__(256, 3) void gemm_pv(
    const u16* __restrict__ P, const u16* __restrict__ Vtb,
    const float* __restrict__ lrow, u16* __restrict__ outp) {
  constexpr int K = 1024, BN = 64, NJ = 2;
  __shared__ u16 As[128 * 64];
  __shared__ u16 Bs[BN * 64];
  const int t = threadIdx.x;
  const int w = t >> 6, l = t & 63, lm = l & 15, lg = l >> 4;
  const int wm = w & 1, wn = w >> 1;
  const int z = blockIdx.z, b = z >> 2, h = z & 3;
  const int m0 = blockIdx.y * 128, n0 = blockIdx.x * BN;
  const u16* Abase = P + ((size_t)z << 20);
  const u16* Bbase = Vtb + ((size_t)z << 18);
  const int rl = l >> 3, gsrc8 = ((l & 7) ^ (rl & 7)) * 8;
  const f32x4 fzero = {0.f, 0.f, 0.f, 0.f};
  f32x4 acc[4][NJ];
#pragma unroll
  for (int i = 0; i < 4; i++)
#pragma unroll
    for (int j = 0; j < NJ; j++) acc[i][j] = fzero;

  for (int kt = 0; kt < K; kt += 64) {
    __syncthreads();
#pragma unroll
    for (int c = 0; c < 4; c++) {
      int rb = c * 32 + w * 8;
      async_copy16(&As[rb * 64], Abase + (size_t)(m0 + rb + rl) * K + kt + gsrc8);
    }
#pragma unroll
    for (int c = 0; c < BN / 32; c++) {
      int rb = c * 32 + w * 8;
      async_copy16(&Bs[rb * 64], Bbase + (size_t)(n0 + rb + rl) * K + kt + gsrc8);
    }
    __syncthreads();
#pragma unroll
    for (int kk = 0; kk < 2; kk++) {
      short8 af[4], bf[NJ];
      const int gph = ((kk * 4 + lg) ^ (lm & 7)) * 8;
#pragma unroll
      for (int i = 0; i < 4; i++)
        af[i] = *(const short8*)&As[(wm * 64 + i * 16 + lm) * 64 + gph];
#pragma unroll
      for (int j = 0; j < NJ; j++)
        bf[j] = *(const short8*)&Bs[(wn * (BN / 2) + j * 16 + lm) * 64 + gph];
#pragma unroll
      for (int i = 0; i < 4; i++)
#pragma unroll
        for (int j = 0; j < NJ; j++) acc[i][j] = MFMA16(af[i], bf[j], acc[i][j]);
    }
  }
#pragma unroll
  for (int i = 0; i < 4; i++) {
    int row0 = m0 + wm * 64 + i * 16 + lg * 4;
    float invl[4];
#pragma unroll
    for (int r = 0; r < 4; r++) invl[r] = 1.f / lrow[(z << 10) + row0 + r];
#pragma unroll
    for (int j = 0; j < NJ; j++) {
      int col = n0 + wn * (BN / 2) + j * 16 + lm;
#pragma unroll
      for (int r = 0; r < 4; r++)
        outp[(size_t)((b << 10) + row0 + r) * 1024 + h * 256 + col] =
            f2bf(acc[i][j][r] * invl[r]);
    }
  }
}

// ---------------------------------------------------------------------------
// MFMA flash attention for the main gated branch (HD=64, NH=16, S=1024).
// Fixed-max online softmax (scores*mod bounded): no max tracking, l deferred.
// 4 waves, BQ=64, BKV=128. 1-D grid of 1024 blocks, XCD-grouped.
__global__ __launch_bounds__(256, 3) void flash_attn64(
    const u16* __restrict__ qkv, const float* __restrict__ modp,
    u16* __restrict__ outp) {
  constexpr int S = 1024, W3 = 3072, HD = 64, BKV = 128;
  constexpr int NKD = 2, NT = 8, ND = 4, NKP = 4, KC = 4;
  constexpr int VSTR = 136, PSTR = 136;

  __shared__ u16 Ks[BKV * HD];
  __shared__ u16 Vt[HD * VSTR];
  __shared__ u16 Ps[64 * PSTR];

  const int t = threadIdx.x, w = t >> 6, l = t & 63, lm = l & 15, lg = l >> 4;
  const int bid = blockIdx.x;
  const int rest = bid >> 3;
  const int q0 = (rest & 15) * 64;
  const int bh = (bid & 7) + 8 * (rest >> 4);    // 0..63
  const int b = bh >> 4, h = bh & 15;
  const size_t rowbase = (size_t)b * S;

  const int oc = t >> 3, kvo = t & 7;
  const int sd0 = (oc & 7) * 8;          // d octet base (OPR=8)
  const int skvg = (oc >> 3) * 8;        // kv group base (KVR=32)

  short8 qf[NKD];
  {
    const u16* qp = qkv + (rowbase + q0 + w * 16 + lm) * W3 + h * HD + lg * 8;
#pragma unroll
    for (int d = 0; d < NKD; d++) qf[d] = *(const short8*)(qp + d * 32);
  }
  float rs[4];
#pragma unroll
  for (int r = 0; r < 4; r++)
    rs[r] = modp[(size_t)bh * S + q0 + w * 16 + lg * 4 + r];

  float lsum[4] = {0.f, 0.f, 0.f, 0.f};
  const f32x4 fzero = {0.f, 0.f, 0.f, 0.f};
  f32x4 oacc[ND];
#pragma unroll
  for (int d = 0; d < ND; d++) oacc[d] = fzero;

  for (int kb = 0; kb < S; kb += BKV) {
    __syncthreads();
    // ---- stage K: async DMA, XOR-granule swizzle on global side (GPR=8,RPW=8)
#pragma unroll
    for (int c = 0; c < 4; c++) {
      int rb = c * 32 + w * 8;
      int row = rb + (l >> 3);
      int gsrc = ((l & 7) ^ (row & 7)) * 8;
      async_copy16(&Ks[rb * HD],
                   qkv + (rowbase + kb + row) * W3 + 1024 + h * HD + gsrc);
    }
    // ---- stage V transposed via in-register 8x8 butterfly
#pragma unroll
    for (int c = 0; c < KC; c++) {
      int kv = c * 32 + skvg + kvo;
      union { short8 s; uint32_t u[4]; } vv, vo;
      vv.s = *(const short8*)(qkv + (rowbase + kb + kv) * W3 + 2048 + h * HD + sd0);
      uint32_t r[4] = {vv.u[0], vv.u[1], vv.u[2], vv.u[3]};
      transpose8x8(r, kvo);
      vo.u[0] = r[0]; vo.u[1] = r[1]; vo.u[2] = r[2]; vo.u[3] = r[3];
      *(short8*)&Vt[(sd0 + kvo) * VSTR + c * 32 + skvg] = vo.s;
    }
    __syncthreads();

    // ---- S = Q K^T
    f32x4 sacc[NT];
#pragma unroll
    for (int n = 0; n < NT; n++) sacc[n] = fzero;
#pragma unroll
    for (int n = 0; n < NT; n++) {
      int krow = n * 16 + lm;
#pragma unroll
      for (int d = 0; d < NKD; d++) {
        int g = d * 4 + lg;
        short8 kf = *(const short8*)&Ks[krow * HD + ((g ^ (krow & 7)) * 8)];
        sacc[n] = MFMA16(qf[d], kf, sacc[n]);
      }
    }
    // ---- fixed-max softmax: p = exp(s*mod); accumulate l lazily per-lane
#pragma unroll
    for (int n = 0; n < NT; n++) {
#pragma unroll
      for (int r = 0; r < 4; r++) {
        float p = __expf(sacc[n][r] * rs[r]);
        lsum[r] += p;
        Ps[(w * 16 + lg * 4 + r) * PSTR + n * 16 + lm] = f2bf(p);
      }
    }
    // ---- O += P V
#pragma unroll
    for (int ks = 0; ks < NKP; ks++) {
      short8 pf = *(const short8*)&Ps[(w * 16 + lm) * PSTR + ks * 32 + lg * 8];
#pragma unroll
      for (int d = 0; d < ND; d++) {
        short8 vf = *(const short8*)&Vt[(d * 16 + lm) * VSTR + ks * 32 + lg * 8];
        oacc[d] = MFMA16(pf, vf, oacc[d]);
      }
    }
  }
  // ---- one butterfly reduction for l, then normalize + store
  float invl[4];
#pragma unroll
  for (int r = 0; r < 4; r++) {
    float s = lsum[r];
#pragma unroll
    for (int sh = 1; sh <= 8; sh <<= 1) s += __shfl_xor(s, sh);
    invl[r] = 1.f / s;
  }
#pragma unroll
  for (int d = 0; d < ND; d++) {
    int col = h * HD + d * 16 + lm;
#pragma unroll
    for (int r = 0; r < 4; r++) {
      int row = q0 + w * 16 + lg * 4 + r;
      outp[(rowbase + row) * 1024 + col] = f2bf(oacc[d][r] * invl[r]);
    }
  }
}

// ---------------------------------------------------------------------------
extern "C" void kernel_launch(void* const* d_in, const int* in_sizes, int n_in,
                              void* d_out, int out_size, void* d_ws, size_t ws_size,
                              hipStream_t stream) {
  (void)in_sizes; (void)n_in; (void)out_size; (void)ws_size;
  const float* X      = (const float*)d_in[0];
  const float* cons   = (const float*)d_in[1];
  const float* Wq     = (const float*)d_in[2];  const float* bq     = (const float*)d_in[3];
  const float* Wk     = (const float*)d_in[4];  const float* bk     = (const float*)d_in[5];
  const float* Wv     = (const float*)d_in[6];  const float* bv     = (const float*)d_in[7];
  const float* cgW    = (const float*)d_in[8];  const float* cgb    = (const float*)d_in[9];
  const float* amW    = (const float*)d_in[10]; const float* amb    = (const float*)d_in[11];
  const float* caWin  = (const float*)d_in[12]; const float* cabin  = (const float*)d_in[13];
  const float* caWout = (const float*)d_in[14]; const float* cabout = (const float*)d_in[15];
  const float* mcWin  = (const float*)d_in[16]; const float* mcbin  = (const float*)d_in[17];
  const float* mcWout = (const float*)d_in[18]; const float* mcbout = (const float*)d_in[19];
  const float* Wo     = (const float*)d_in[20]; const float* bo     = (const float*)d_in[21];

  char* ws = (char*)d_ws;
  size_t off = 0;
  auto alloc = [&](size_t bytes) -> void* {
    void* p = ws + off; off += (bytes + 255) & ~(size_t)255; return p;
  };
  u16*    Xbf     = (u16*)alloc((size_t)4096 * 1024 * 2);
  u16*    WqkvT   = (u16*)alloc((size_t)3072 * 1024 * 2);
  u16*    caWinT  = (u16*)alloc((size_t)3072 * 1024 * 2);
  u16*    mcWinT  = (u16*)alloc((size_t)3072 * 1024 * 2);
  u16*    caWoutT = (u16*)alloc((size_t)1024 * 1024 * 2);
  u16*    mcWoutT = (u16*)alloc((size_t)1024 * 1024 * 2);
  u16*    WoT     = (u16*)alloc((size_t)1024 * 1024 * 2);
  float*  bqkv    = (float*)alloc(3072 * 4);
  float*  modb    = (float*)alloc((size_t)64 * 1024 * 4);
  u16*    big0    = (u16*)alloc((size_t)4096 * 3072 * 2);        // CAqk | QKVm | MCqk
  u16*    actx    = (u16*)alloc((size_t)4096 * 1024 * 2);
  u16*    ctxm    = (u16*)alloc((size_t)4096 * 1024 * 2);
  u16*    ctx1    = (u16*)alloc((size_t)4096 * 1024 * 2);
  u16*    Pbuf    = (u16*)alloc((size_t)16 * 1024 * 1024 * 2);   // 32 MB
  u16*    Vtb     = (u16*)alloc((size_t)16 * 256 * 1024 * 2);    // 8 MB
  float*  lbuf    = (float*)alloc((size_t)2 * 16384 * 4);        // l_ca | l_mc
  float*  l_ca    = lbuf;
  float*  l_mc    = lbuf + 16384;
  u16*    mctx    = ctxm;  // alias: ctxm dead after blend1
  u16*    ctx2    = actx;  // alias: actx dead after blend1

  // ---- prep
  castmod_kernel<<<4096, 256, 0, stream>>>(X, Xbf, cgW, cgb, cons, amW, amb, modb);
  {
    TBatch b6;
    b6.src[0] = Wq;     b6.dst[0] = WqkvT;
    b6.src[1] = Wk;     b6.dst[1] = WqkvT + (size_t)1024 * 1024;
    b6.src[2] = Wv;     b6.dst[2] = WqkvT + (size_t)2048 * 1024;
    b6.src[3] = caWout; b6.dst[3] = caWoutT;
    b6.src[4] = mcWout; b6.dst[4] = mcWoutT;
    b6.src[5] = Wo;     b6.dst[5] = WoT;
    transpose_cast_batch<<<dim3(32, 32, 6), dim3(32, 8), 0, stream>>>(b6, 1024, 1024);
    TBatch b2;
    b2.src[0] = caWin;  b2.dst[0] = caWinT;
    b2.src[1] = mcWin;  b2.dst[1] = mcWinT;
    b2.src[2] = b2.src[3] = b2.src[4] = b2.src[5] = nullptr;
    b2.dst[2] = b2.dst[3] = b2.dst[4] = b2.dst[5] = nullptr;
    transpose_cast_batch<<<dim3(96, 32, 2), dim3(32, 8), 0, stream>>>(b2, 1024, 3072);
  }
  pack_bias3<<<12, 256, 0, stream>>>(bq, bk, bv, bqkv);
  zero_f32<<<128, 256, 0, stream>>>(lbuf);

  // ---- causal branch: QK in-proj, V^T in-proj, exp-GEMM, PV-GEMM
  gemm_bt<0, 0, 128><<<dim3(16, 32), 256, 0, stream>>>(Xbf, caWinT, cabin, nullptr, 0.f, 0.f,
                                                       big0, 4096, 3072, 1024);
  gemm_vt<<<dim3(8, 32), 256, 0, stream>>>(Xbf, caWinT + (size_t)2048 * 1024,
                                           cabin + 2048, Vtb);
  gemm_qk_exp<<<dim3(8, 8, 16), 256, 0, stream>>>(big0, Pbuf, l_ca, 1.f / 16.f);
  gemm_pv<<<dim3(4, 8, 16), 256, 0, stream>>>(Pbuf, Vtb, l_ca, actx);

  // ---- main QKV + gated flash attention
  gemm_bt<0, 0, 128><<<dim3(24, 32), 256, 0, stream>>>(Xbf, WqkvT, bqkv, nullptr, 0.f, 0.f,
                                                       big0, 4096, 3072, 1024);
  flash_attn64<<<1024, 256, 0, stream>>>(big0, modb, ctxm);

  // ctx1 = 0.3*ctxm + 0.7*(actx@caWout + cabout)
  gemm_bt<0, 1, 64><<<dim3(16, 32), 256, 0, stream>>>(actx, caWoutT, cabout, ctxm, 0.7f, 0.3f,
                                                      ctx1, 4096, 1024, 1024);

  // ---- meta branch
  gemm_bt<0, 0, 128><<<dim3(16, 32), 256, 0, stream>>>(ctx1, mcWinT, mcbin, nullptr, 0.f, 0.f,
                                                       big0, 4096, 3072, 1024);
  gemm_vt<<<dim3(8, 32), 256, 0, stream>>>(ctx1, mcWinT + (size_t)2048 * 1024,
                                           mcbin + 2048, Vtb);
  gemm_qk_exp<<<dim3(8, 8, 16), 256, 0, stream>>>(big0, Pbuf, l_mc, 1.f / 16.f);
  gemm_pv<<<dim3(4, 8, 16), 256, 0, stream>>>(Pbuf, Vtb, l_mc, mctx);

  // ctx2 = 0.85*ctx1 + 0.15*(mctx@mcWout + mcbout)
  gemm_bt<0, 1, 64><<<dim3(16, 32), 256, 0, stream>>>(mctx, mcWoutT, mcbout, ctx1, 0.15f, 0.85f,
                                                      ctx2, 4096, 1024, 1024);
  // out = ctx2@Wo + bo (fp32)
  gemm_bt<1, 0, 64><<<dim3(16, 32), 256, 0, stream>>>(ctx2, WoT, bo, nullptr, 0.f, 0.f,
                                                      d_out, 4096, 1024, 1024);
}

// Round 5
// 442.571 us; speedup vs baseline: 1.3103x; 1.0900x over previous
//
#include <hip/hip_runtime.h>
#include <stdint.h>

typedef unsigned short u16;
typedef __attribute__((ext_vector_type(8))) short short8;   // 8 x bf16 (4 VGPRs)
typedef __attribute__((ext_vector_type(4))) float f32x4;    // MFMA accumulator

#define MFMA16(a,b,c) __builtin_amdgcn_mfma_f32_16x16x32_bf16((a),(b),(c),0,0,0)

__device__ __forceinline__ u16 f2bf(float f) {
  union { float f; uint32_t u; } v; v.f = f;
  uint32_t r = v.u + 0x7FFFu + ((v.u >> 16) & 1u);   // RNE
  return (u16)(r >> 16);
}
__device__ __forceinline__ float bf2f(uint32_t u) {
  union { uint32_t i; float f; } v; v.i = u << 16; return v.f;
}
// async global->LDS, 16B per lane; LDS dest = wave-uniform base + lane*16
__device__ __forceinline__ void async_copy16(void* lds, const void* g) {
  __builtin_amdgcn_global_load_lds(
      (const __attribute__((address_space(1))) uint32_t*)g,
      (__attribute__((address_space(3))) uint32_t*)lds, 16, 0, 0);
}

// in-register 8x8 u16 transpose across 8 lanes (lane8 = lane&7), 4 u32 regs
__device__ __forceinline__ void transpose8x8(uint32_t r[4], int lane8) {
  uint32_t a0, a1, a2, a3;
  a0 = __shfl_xor(r[0], 4); a1 = __shfl_xor(r[1], 4);
  a2 = __shfl_xor(r[2], 4); a3 = __shfl_xor(r[3], 4);
  if (lane8 & 4) { r[0] = a2; r[1] = a3; } else { r[2] = a0; r[3] = a1; }
  a0 = __shfl_xor(r[0], 2); a1 = __shfl_xor(r[1], 2);
  a2 = __shfl_xor(r[2], 2); a3 = __shfl_xor(r[3], 2);
  if (lane8 & 2) { r[0] = a1; r[2] = a3; } else { r[1] = a0; r[3] = a2; }
  a0 = __shfl_xor(r[0], 1); a1 = __shfl_xor(r[1], 1);
  a2 = __shfl_xor(r[2], 1); a3 = __shfl_xor(r[3], 1);
  uint32_t sel = (lane8 & 1) ? 0x03020706u : 0x05040100u;
  r[0] = __builtin_amdgcn_perm(a0, r[0], sel);
  r[1] = __builtin_amdgcn_perm(a1, r[1], sel);
  r[2] = __builtin_amdgcn_perm(a2, r[2], sel);
  r[3] = __builtin_amdgcn_perm(a3, r[3], sel);
}

// ---------------------------------------------------------------------------
// fused: Xbf = bf16(X);  mod[b*16+h][s] = sigmoid(X@cgW + cgb + cons@amW + amb)/8
__global__ __launch_bounds__(256) void castmod_kernel(
    const float* __restrict__ X, u16* __restrict__ Xbf,
    const float* __restrict__ cgW, const float* __restrict__ cgb,
    const float* __restrict__ cons, const float* __restrict__ amW,
    const float* __restrict__ amb, float* __restrict__ modp) {
  __shared__ float xs[1024];
  __shared__ float part[16][16];
  __shared__ float am[16];
  int row = blockIdx.x, t = threadIdx.x;
  {
    float4 v = ((const float4*)(X + (size_t)row * 1024))[t];
    xs[t * 4 + 0] = v.x; xs[t * 4 + 1] = v.y; xs[t * 4 + 2] = v.z; xs[t * 4 + 3] = v.w;
    uint2 o;
    o.x = (uint32_t)f2bf(v.x) | ((uint32_t)f2bf(v.y) << 16);
    o.y = (uint32_t)f2bf(v.z) | ((uint32_t)f2bf(v.w) << 16);
    ((uint2*)Xbf)[(size_t)row * 256 + t] = o;
  }
  if (t < 16) {
    float a = amb[t];
#pragma unroll
    for (int i = 0; i < 16; i++) a += cons[i] * amW[i * 16 + t];
    am[t] = a;
  }
  __syncthreads();
  int h = t & 15, ch = t >> 4;
  float p = 0.f;
#pragma unroll 8
  for (int k = ch * 64; k < ch * 64 + 64; k++) p += xs[k] * cgW[k * 16 + h];
  part[ch][h] = p;
  __syncthreads();
  if (t < 16) {
    float s = cgb[t] + am[t];
#pragma unroll
    for (int c = 0; c < 16; c++) s += part[c][t];
    int b = row >> 10, si = row & 1023;
    modp[((size_t)(b * 16 + t)) * 1024 + si] = 0.125f / (1.f + __expf(-s));
  }
}

// ---------------------------------------------------------------------------
// all weight prep in one kernel: 12 transpose+cast slices (z<12) + misc (z=12):
// biasBig concat + lbuf zeroing.
struct PrepArgs {
  const float* src[12];
  u16* dst[12];
  int sstride[12];
  const float* cabin; const float* bq; const float* bk; const float* bv;
  float* biasBig; float* lbuf;
};
__global__ __launch_bounds__(256) void prep_weights(PrepArgs p) {
  int z = blockIdx.z;
  int tx = threadIdx.x & 31, ty = threadIdx.x >> 5;   // (32,8) logical
  if (z < 12) {
    __shared__ float tile[32][33];
    const float* __restrict__ in = p.src[z];
    u16* __restrict__ out = p.dst[z];
    int sstr = p.sstride[z];
    int c0 = blockIdx.x * 32, r0 = blockIdx.y * 32;
#pragma unroll
    for (int j = 0; j < 4; j++)
      tile[ty + j * 8][tx] = in[(size_t)(r0 + ty + j * 8) * sstr + c0 + tx];
    __syncthreads();
#pragma unroll
    for (int j = 0; j < 4; j++)
      out[(size_t)(c0 + ty + j * 8) * 1024 + r0 + tx] = f2bf(tile[tx][ty + j * 8]);
  } else {
    int id = blockIdx.y * 32 + blockIdx.x, t = threadIdx.x;
    if (id < 24) {
      int i = id * 256 + t;   // 0..6143
      float v;
      if (i < 3072) v = p.cabin[i];
      else if (i < 4096) v = p.bq[i - 3072];
      else if (i < 5120) v = p.bk[i - 4096];
      else v = p.bv[i - 5120];
      p.biasBig[i] = v;
    } else if (id < 152) {
      p.lbuf[(id - 24) * 256 + t] = 0.f;
    }
  }
}

// ---------------------------------------------------------------------------
// bf16 GEMM, BK=64: C[M,N] = A[M,K] @ Bt[N,K]^T (+bias, optional blend)
// 128xBN tile, 4 waves. XOR-granule swizzle on the GLOBAL side of async
// staging; reads un-swizzle.
template <int OUT_F32, int HAS_EXTRA, int BN>
__global__ __launch_bounds__(256, 3) void gemm_bt(
    const u16* __restrict__ A, const u16* __restrict__ Bt,
    const float* __restrict__ bias, const u16* __restrict__ extra,
    float alpha, float beta, void* __restrict__ Cout, int M, int N, int K) {
  constexpr int NJ = BN / 32;   // j-tiles per wave
  __shared__ u16 As[128 * 64];
  __shared__ u16 Bs[BN * 64];
  const int t = threadIdx.x;
  const int w = t >> 6, l = t & 63, lm = l & 15, lg = l >> 4;
  const int wm = w & 1, wn = w >> 1;
  const int m0 = blockIdx.y * 128, n0 = blockIdx.x * BN;
  const int rl = l >> 3, gsrc8 = ((l & 7) ^ (rl & 7)) * 8;
  const f32x4 fzero = {0.f, 0.f, 0.f, 0.f};
  f32x4 acc[4][NJ];
#pragma unroll
  for (int i = 0; i < 4; i++)
#pragma unroll
    for (int j = 0; j < NJ; j++) acc[i][j] = fzero;

  for (int kt = 0; kt < K; kt += 64) {
    __syncthreads();
#pragma unroll
    for (int c = 0; c < 4; c++) {       // A: 128 rows x 64 cols
      int rb = c * 32 + w * 8;
      async_copy16(&As[rb * 64], A + (size_t)(m0 + rb + rl) * K + kt + gsrc8);
    }
#pragma unroll
    for (int c = 0; c < BN / 32; c++) { // B: BN rows x 64 cols
      int rb = c * 32 + w * 8;
      async_copy16(&Bs[rb * 64], Bt + (size_t)(n0 + rb + rl) * K + kt + gsrc8);
    }
    __syncthreads();
#pragma unroll
    for (int kk = 0; kk < 2; kk++) {
      short8 af[4], bf[NJ];
      const int gph = ((kk * 4 + lg) ^ (lm & 7)) * 8;
#pragma unroll
      for (int i = 0; i < 4; i++)
        af[i] = *(const short8*)&As[(wm * 64 + i * 16 + lm) * 64 + gph];
#pragma unroll
      for (int j = 0; j < NJ; j++)
        bf[j] = *(const short8*)&Bs[(wn * (BN / 2) + j * 16 + lm) * 64 + gph];
#pragma unroll
      for (int i = 0; i < 4; i++)
#pragma unroll
        for (int j = 0; j < NJ; j++) acc[i][j] = MFMA16(af[i], bf[j], acc[i][j]);
    }
  }
#pragma unroll
  for (int i = 0; i < 4; i++) {
    int row0 = m0 + wm * 64 + i * 16 + lg * 4;
#pragma unroll
    for (int j = 0; j < NJ; j++) {
      int col = n0 + wn * (BN / 2) + j * 16 + lm;
      float bc = bias[col];
#pragma unroll
      for (int r = 0; r < 4; r++) {
        size_t idx = (size_t)(row0 + r) * N + col;
        float v = acc[i][j][r] + bc;
        if constexpr (HAS_EXTRA) v = alpha * v + beta * bf2f(extra[idx]);
        if constexpr (OUT_F32) ((float*)Cout)[idx] = v;
        else ((u16*)Cout)[idx] = f2bf(v);
      }
    }
  }
}

// ---------------------------------------------------------------------------
// mega in-projection: C[4096][N] = Xbf @ BtBig^T + bias, N = gridDim.x*128.
// Epilogue routes by column region:
//   col <  2048          -> qkOut[row][col]           (stride 2048; Q|K halves)
//   2048 <= col < 3072   -> Vtb[z=(row>>10)*4+head][d][q]  (transposed store)
//   col >= 3072          -> qkvm[row][col-3072]       (stride 3072, main QKV)
__global__ __launch_bounds__(256, 3) void gemm_in3(
    const u16* __restrict__ A, const u16* __restrict__ BtBig,
    const float* __restrict__ bias, u16* __restrict__ qkOut,
    u16* __restrict__ Vtb, u16* __restrict__ qkvm) {
  constexpr int K = 1024;
  __shared__ u16 As[128 * 64];
  __shared__ u16 Bs[128 * 64];
  const int t = threadIdx.x;
  const int w = t >> 6, l = t & 63, lm = l & 15, lg = l >> 4;
  const int wm = w & 1, wn = w >> 1;
  const int m0 = blockIdx.y * 128, n0 = blockIdx.x * 128;
  const int rl = l >> 3, gsrc8 = ((l & 7) ^ (rl & 7)) * 8;
  const f32x4 fzero = {0.f, 0.f, 0.f, 0.f};
  f32x4 acc[4][4];
#pragma unroll
  for (int i = 0; i < 4; i++)
#pragma unroll
    for (int j = 0; j < 4; j++) acc[i][j] = fzero;

  for (int kt = 0; kt < K; kt += 64) {
    __syncthreads();
#pragma unroll
    for (int c = 0; c < 4; c++) {
      int rb = c * 32 + w * 8;
      async_copy16(&As[rb * 64], A + (size_t)(m0 + rb + rl) * K + kt + gsrc8);
      async_copy16(&Bs[rb * 64], BtBig + (size_t)(n0 + rb + rl) * K + kt + gsrc8);
    }
    __syncthreads();
#pragma unroll
    for (int kk = 0; kk < 2; kk++) {
      short8 af[4], bf[4];
      const int gph = ((kk * 4 + lg) ^ (lm & 7)) * 8;
#pragma unroll
      for (int i = 0; i < 4; i++)
        af[i] = *(const short8*)&As[(wm * 64 + i * 16 + lm) * 64 + gph];
#pragma unroll
      for (int j = 0; j < 4; j++)
        bf[j] = *(const short8*)&Bs[(wn * 64 + j * 16 + lm) * 64 + gph];
#pragma unroll
      for (int i = 0; i < 4; i++)
#pragma unroll
        for (int j = 0; j < 4; j++) acc[i][j] = MFMA16(af[i], bf[j], acc[i][j]);
    }
  }
#pragma unroll
  for (int i = 0; i < 4; i++) {
    int row0 = m0 + wm * 64 + i * 16 + lg * 4;
#pragma unroll
    for (int j = 0; j < 4; j++) {
      int col = n0 + wn * 64 + j * 16 + lm;
      float bc = bias[col];
      if (col < 2048) {
#pragma unroll
        for (int r = 0; r < 4; r++)
          qkOut[(size_t)(row0 + r) * 2048 + col] = f2bf(acc[i][j][r] + bc);
      } else if (col < 3072) {
        int b = row0 >> 10, q0 = row0 & 1023;
        int z = b * 4 + ((col - 2048) >> 8), d = (col - 2048) & 255;
        union { u16 pk[4]; uint2 v; } u;
#pragma unroll
        for (int r = 0; r < 4; r++) u.pk[r] = f2bf(acc[i][j][r] + bc);
        *(uint2*)&Vtb[((size_t)z * 256 + d) * 1024 + q0] = u.v;
      } else {
#pragma unroll
        for (int r = 0; r < 4; r++)
          qkvm[(size_t)(row0 + r) * 3072 + col - 3072] = f2bf(acc[i][j][r] + bc);
      }
    }
  }
}

// ---------------------------------------------------------------------------
// batched QK^T with exp epilogue + fused row-sum atomics (fixed-max softmax).
// z: b=z>>2, h=z&3. Q at qk[b*1024..][h*256], K at +1024 cols. stride 2048.
// P[z][q][kv] = exp(acc*scale) bf16;  lrow[z][q] += rowsum (pre-zeroed).
__global__ __launch_bounds__(256, 3) void gemm_qk_exp(
    const u16* __restrict__ qk, u16* __restrict__ P, float* __restrict__ lrow,
    float scale) {
  constexpr int QKS = 2048;
  __shared__ u16 As[128 * 64];
  __shared__ u16 Bs[128 * 64];
  const int t = threadIdx.x;
  const int w = t >> 6, l = t & 63, lm = l & 15, lg = l >> 4;
  const int wm = w & 1, wn = w >> 1;
  const int z = blockIdx.z, b = z >> 2, h = z & 3;
  const int m0 = blockIdx.y * 128, n0 = blockIdx.x * 128;
  const u16* Abase = qk + ((size_t)b << 10) * QKS + h * 256;          // Q
  const u16* Bbase = qk + ((size_t)b << 10) * QKS + 1024 + h * 256;   // K
  const int rl = l >> 3, gsrc8 = ((l & 7) ^ (rl & 7)) * 8;
  const f32x4 fzero = {0.f, 0.f, 0.f, 0.f};
  f32x4 acc[4][4];
#pragma unroll
  for (int i = 0; i < 4; i++)
#pragma unroll
    for (int j = 0; j < 4; j++) acc[i][j] = fzero;

#pragma unroll
  for (int kt = 0; kt < 256; kt += 64) {
    __syncthreads();
#pragma unroll
    for (int c = 0; c < 4; c++) {
      int rb = c * 32 + w * 8;
      async_copy16(&As[rb * 64], Abase + (size_t)(m0 + rb + rl) * QKS + kt + gsrc8);
      async_copy16(&Bs[rb * 64], Bbase + (size_t)(n0 + rb + rl) * QKS + kt + gsrc8);
    }
    __syncthreads();
#pragma unroll
    for (int kk = 0; kk < 2; kk++) {
      short8 af[4], bf[4];
      const int gph = ((kk * 4 + lg) ^ (lm & 7)) * 8;
#pragma unroll
      for (int i = 0; i < 4; i++)
        af[i] = *(const short8*)&As[(wm * 64 + i * 16 + lm) * 64 + gph];
#pragma unroll
      for (int j = 0; j < 4; j++)
        bf[j] = *(const short8*)&Bs[(wn * 64 + j * 16 + lm) * 64 + gph];
#pragma unroll
      for (int i = 0; i < 4; i++)
#pragma unroll
        for (int j = 0; j < 4; j++) acc[i][j] = MFMA16(af[i], bf[j], acc[i][j]);
    }
  }
  // epilogue: P = exp(acc*scale), rowsum via lane-reduce + atomicAdd
  u16* Pz = P + ((size_t)z << 20);
#pragma unroll
  for (int i = 0; i < 4; i++) {
    int row0 = m0 + wm * 64 + i * 16 + lg * 4;
    float rsum[4] = {0.f, 0.f, 0.f, 0.f};
#pragma unroll
    for (int j = 0; j < 4; j++) {
      int col = n0 + wn * 64 + j * 16 + lm;
#pragma unroll
      for (int r = 0; r < 4; r++) {
        float p = __expf(acc[i][j][r] * scale);
        rsum[r] += p;
        Pz[(size_t)(row0 + r) * 1024 + col] = f2bf(p);
      }
    }
#pragma unroll
    for (int r = 0; r < 4; r++) {
      float s = rsum[r];
#pragma unroll
      for (int sh = 1; sh <= 8; sh <<= 1) s += __shfl_xor(s, sh);
      if (lm == 0) atomicAdd(&lrow[(z << 10) + row0 + r], s);
    }
  }
}

// ---------------------------------------------------------------------------
// batched PV: O[q][d] = (P[z] @ Vtb[z]^T) / l, stored into ctx[B*S][1024] at
// col h*256. A=P[z] (M=1024,K=1024,str 1024), Bt=Vtb[z] (256 rows,str 1024).
__global__ __launch_bounds__(256, 3) void gemm_pv(
    const u16* __restrict__ P, const u16* __restrict__ Vtb,
    const float* __restrict__ lrow, u16* __restrict__ outp) {
  constexpr int K = 1024, BN = 64, NJ = 2;
  __shared__ u16 As[128 * 64];
  __shared__ u16 Bs[BN * 64];
  const int t = threadIdx.x;
  const int w = t >> 6, l = t & 63, lm = l & 15, lg = l >> 4;
  const int wm = w & 1, wn = w >> 1;
  const int z = blockIdx.z, b = z >> 2, h = z & 3;
  const int m0 = blockIdx.y * 128, n0 = blockIdx.x * BN;
  const u16* Abase = P + ((size_t)z << 20);
  const u16* Bbase = Vtb + ((size_t)z << 18);
  const int rl = l >> 3, gsrc8 = ((l & 7) ^ (rl & 7)) * 8;
  const f32x4 fzero = {0.f, 0.f, 0.f, 0.f};
  f32x4 acc[4][NJ];
#pragma unroll
  for (int i = 0; i < 4; i++)
#pragma unroll
    for (int j = 0; j < NJ; j++) acc[i][j] = fzero;

  for (int kt = 0; kt < K; kt += 64) {
    __syncthreads();
#pragma unroll
    for (int c = 0; c < 4; c++) {
      int rb = c * 32 + w * 8;
      async_copy16(&As[rb * 64], Abase + (size_t)(m0 + rb + rl) * K + kt + gsrc8);
    }
#pragma unroll
    for (int c = 0; c < BN / 32; c++) {
      int rb = c * 32 + w * 8;
      async_copy16(&Bs[rb * 64], Bbase + (size_t)(n0 + rb + rl) * K + kt + gsrc8);
    }
    __syncthreads();
#pragma unroll
    for (int kk = 0; kk < 2; kk++) {
      short8 af[4], bf[NJ];
      const int gph = ((kk * 4 + lg) ^ (lm & 7)) * 8;
#pragma unroll
      for (int i = 0; i < 4; i++)
        af[i] = *(const short8*)&As[(wm * 64 + i * 16 + lm) * 64 + gph];
#pragma unroll
      for (int j = 0; j < NJ; j++)
        bf[j] = *(const short8*)&Bs[(wn * (BN / 2) + j * 16 + lm) * 64 + gph];
#pragma unroll
      for (int i = 0; i < 4; i++)
#pragma unroll
        for (int j = 0; j < NJ; j++) acc[i][j] = MFMA16(af[i], bf[j], acc[i][j]);
    }
  }
#pragma unroll
  for (int i = 0; i < 4; i++) {
    int row0 = m0 + wm * 64 + i * 16 + lg * 4;
    float invl[4];
#pragma unroll
    for (int r = 0; r < 4; r++) invl[r] = 1.f / lrow[(z << 10) + row0 + r];
#pragma unroll
    for (int j = 0; j < NJ; j++) {
      int col = n0 + wn * (BN / 2) + j * 16 + lm;
#pragma unroll
      for (int r = 0; r < 4; r++)
        outp[(size_t)((b << 10) + row0 + r) * 1024 + h * 256 + col] =
            f2bf(acc[i][j][r] * invl[r]);
    }
  }
}

// ---------------------------------------------------------------------------
// MFMA flash attention, main gated branch (HD=64, NH=16, S=1024). BQ=128
// (each wave owns 2 q-fragments), BKV=128, fixed-max softmax. Grid 512,
// XCD-grouped: all 8 q-blocks of a bh share one XCD (K/V L2 reuse).
__global__ __launch_bounds__(256, 2) void flash_attn64(
    const u16* __restrict__ qkv, const float* __restrict__ modp,
    u16* __restrict__ outp) {
  constexpr int S = 1024, W3 = 3072, HD = 64, BKV = 128;
  constexpr int NKD = 2, NT = 8, ND = 4, NKP = 4, KC = 4;
  constexpr int VSTR = 136, PSTR = 136;

  __shared__ u16 Ks[BKV * HD];      // 16 KB
  __shared__ u16 Vt[HD * VSTR];     // 17 KB
  __shared__ u16 Ps[128 * PSTR];    // 34.8 KB

  const int t = threadIdx.x, w = t >> 6, l = t & 63, lm = l & 15, lg = l >> 4;
  const int bid = blockIdx.x;
  const int rest = bid >> 3;
  const int q0 = (rest & 7) * 128;
  const int bh = (bid & 7) + 8 * (rest >> 3);    // 0..63
  const int b = bh >> 4, h = bh & 15;
  const size_t rowbase = (size_t)b * S;

  const int oc = t >> 3, kvo = t & 7;
  const int sd0 = (oc & 7) * 8;          // d octet base (OPR=8)
  const int skvg = (oc >> 3) * 8;        // kv group base (KVR=32)

  short8 qf[2][NKD];
  float rs[2][4];
#pragma unroll
  for (int qs = 0; qs < 2; qs++) {
    const u16* qp = qkv + (rowbase + q0 + qs * 64 + w * 16 + lm) * W3 + h * HD + lg * 8;
#pragma unroll
    for (int d = 0; d < NKD; d++) qf[qs][d] = *(const short8*)(qp + d * 32);
#pragma unroll
    for (int r = 0; r < 4; r++)
      rs[qs][r] = modp[(size_t)bh * S + q0 + qs * 64 + w * 16 + lg * 4 + r];
  }

  float lsum[2][4] = {{0.f, 0.f, 0.f, 0.f}, {0.f, 0.f, 0.f, 0.f}};
  const f32x4 fzero = {0.f, 0.f, 0.f, 0.f};
  f32x4 oacc[2][ND];
#pragma unroll
  for (int qs = 0; qs < 2; qs++)
#pragma unroll
    for (int d = 0; d < ND; d++) oacc[qs][d] = fzero;

  for (int kb = 0; kb < S; kb += BKV) {
    __syncthreads();
    // ---- stage K: async DMA, XOR-granule swizzle on global side
#pragma unroll
    for (int c = 0; c < 4; c++) {
      int rb = c * 32 + w * 8;
      int row = rb + (l >> 3);
      int gsrc = ((l & 7) ^ (row & 7)) * 8;
      async_copy16(&Ks[rb * HD],
                   qkv + (rowbase + kb + row) * W3 + 1024 + h * HD + gsrc);
    }
    // ---- stage V transposed via in-register 8x8 butterfly
#pragma unroll
    for (int c = 0; c < KC; c++) {
      int kv = c * 32 + skvg + kvo;
      union { short8 s; uint32_t u[4]; } vv, vo;
      vv.s = *(const short8*)(qkv + (rowbase + kb + kv) * W3 + 2048 + h * HD + sd0);
      uint32_t r[4] = {vv.u[0], vv.u[1], vv.u[2], vv.u[3]};
      transpose8x8(r, kvo);
      vo.u[0] = r[0]; vo.u[1] = r[1]; vo.u[2] = r[2]; vo.u[3] = r[3];
      *(short8*)&Vt[(sd0 + kvo) * VSTR + c * 32 + skvg] = vo.s;
    }
    __syncthreads();

    // ---- per q-fragment: S = Q K^T, then p=exp(s*mod) -> Ps (same-wave rows)
#pragma unroll
    for (int qs = 0; qs < 2; qs++) {
      f32x4 sacc[NT];
#pragma unroll
      for (int n = 0; n < NT; n++) sacc[n] = fzero;
#pragma unroll
      for (int n = 0; n < NT; n++) {
        int krow = n * 16 + lm;
#pragma unroll
        for (int d = 0; d < NKD; d++) {
          int g = d * 4 + lg;
          short8 kf = *(const short8*)&Ks[krow * HD + ((g ^ (krow & 7)) * 8)];
          sacc[n] = MFMA16(qf[qs][d], kf, sacc[n]);
        }
      }
#pragma unroll
      for (int n = 0; n < NT; n++) {
#pragma unroll
        for (int r = 0; r < 4; r++) {
          float p = __expf(sacc[n][r] * rs[qs][r]);
          lsum[qs][r] += p;
          Ps[(qs * 64 + w * 16 + lg * 4 + r) * PSTR + n * 16 + lm] = f2bf(p);
        }
      }
    }
    // ---- O += P V
#pragma unroll
    for (int qs = 0; qs < 2; qs++) {
#pragma unroll
      for (int ks = 0; ks < NKP; ks++) {
        short8 pf = *(const short8*)&Ps[(qs * 64 + w * 16 + lm) * PSTR + ks * 32 + lg * 8];
#pragma unroll
        for (int d = 0; d < ND; d++) {
          short8 vf = *(const short8*)&Vt[(d * 16 + lm) * VSTR + ks * 32 + lg * 8];
          oacc[qs][d] = MFMA16(pf, vf, oacc[qs][d]);
        }
      }
    }
  }
  // ---- one butterfly reduction for l, then normalize + store
#pragma unroll
  for (int qs = 0; qs < 2; qs++) {
    float invl[4];
#pragma unroll
    for (int r = 0; r < 4; r++) {
      float s = lsum[qs][r];
#pragma unroll
      for (int sh = 1; sh <= 8; sh <<= 1) s += __shfl_xor(s, sh);
      invl[r] = 1.f / s;
    }
#pragma unroll
    for (int d = 0; d < ND; d++) {
      int col = h * HD + d * 16 + lm;
#pragma unroll
      for (int r = 0; r < 4; r++) {
        int row = q0 + qs * 64 + w * 16 + lg * 4 + r;
        outp[(rowbase + row) * 1024 + col] = f2bf(oacc[qs][d][r] * invl[r]);
      }
    }
  }
}

// ---------------------------------------------------------------------------
extern "C" void kernel_launch(void* const* d_in, const int* in_sizes, int n_in,
                              void* d_out, int out_size, void* d_ws, size_t ws_size,
                              hipStream_t stream) {
  (void)in_sizes; (void)n_in; (void)out_size; (void)ws_size;
  const float* X      = (const float*)d_in[0];
  const float* cons   = (const float*)d_in[1];
  const float* Wq     = (const float*)d_in[2];  const float* bq     = (const float*)d_in[3];
  const float* Wk     = (const float*)d_in[4];  const float* bk     = (const float*)d_in[5];
  const float* Wv     = (const float*)d_in[6];  const float* bv     = (const float*)d_in[7];
  const float* cgW    = (const float*)d_in[8];  const float* cgb    = (const float*)d_in[9];
  const float* amW    = (const float*)d_in[10]; const float* amb    = (const float*)d_in[11];
  const float* caWin  = (const float*)d_in[12]; const float* cabin  = (const float*)d_in[13];
  const float* caWout = (const float*)d_in[14]; const float* cabout = (const float*)d_in[15];
  const float* mcWin  = (const float*)d_in[16]; const float* mcbin  = (const float*)d_in[17];
  const float* mcWout = (const float*)d_in[18]; const float* mcbout = (const float*)d_in[19];
  const float* Wo     = (const float*)d_in[20]; const float* bo     = (const float*)d_in[21];

  char* ws = (char*)d_ws;
  size_t off = 0;
  auto alloc = [&](size_t bytes) -> void* {
    void* p = ws + off; off += (bytes + 255) & ~(size_t)255; return p;
  };
  u16*    Xbf     = (u16*)alloc((size_t)4096 * 1024 * 2);
  u16*    BtBig   = (u16*)alloc((size_t)6144 * 1024 * 2);        // caWin^T | Wqkv^T
  u16*    mcWinT  = (u16*)alloc((size_t)3072 * 1024 * 2);
  u16*    caWoutT = (u16*)alloc((size_t)1024 * 1024 * 2);
  u16*    mcWoutT = (u16*)alloc((size_t)1024 * 1024 * 2);
  u16*    WoT     = (u16*)alloc((size_t)1024 * 1024 * 2);
  float*  biasBig = (float*)alloc(6144 * 4);
  float*  modb    = (float*)alloc((size_t)64 * 1024 * 4);
  u16*    caQK    = (u16*)alloc((size_t)4096 * 2048 * 2);        // also mcQK
  u16*    qkvm    = (u16*)alloc((size_t)4096 * 3072 * 2);
  u16*    actx    = (u16*)alloc((size_t)4096 * 1024 * 2);
  u16*    ctxm    = (u16*)alloc((size_t)4096 * 1024 * 2);
  u16*    ctx1    = (u16*)alloc((size_t)4096 * 1024 * 2);
  u16*    Pbuf    = (u16*)alloc((size_t)16 * 1024 * 1024 * 2);   // 32 MB
  u16*    Vtb     = (u16*)alloc((size_t)16 * 256 * 1024 * 2);    // 8 MB
  float*  lbuf    = (float*)alloc((size_t)2 * 16384 * 4);        // l_ca | l_mc
  float*  l_ca    = lbuf;
  float*  l_mc    = lbuf + 16384;
  u16*    mcQK    = caQK;  // alias: caQK dead after qk_exp ca
  u16*    mctx    = ctxm;  // alias: ctxm dead after blend1
  u16*    ctx2    = actx;  // alias: actx dead after blend1

  // ---- prep (2 launches)
  castmod_kernel<<<4096, 256, 0, stream>>>(X, Xbf, cgW, cgb, cons, amW, amb, modb);
  {
    PrepArgs pa;
    // BtBig rows 0..3071 = caWin^T (3 slices), rows 3072..6143 = Wq^T|Wk^T|Wv^T
    for (int s = 0; s < 3; s++) {
      pa.src[s] = caWin + s * 1024; pa.dst[s] = BtBig + (size_t)s * 1024 * 1024;
      pa.sstride[s] = 3072;
    }
    pa.src[3] = Wq; pa.dst[3] = BtBig + (size_t)3072 * 1024; pa.sstride[3] = 1024;
    pa.src[4] = Wk; pa.dst[4] = BtBig + (size_t)4096 * 1024; pa.sstride[4] = 1024;
    pa.src[5] = Wv; pa.dst[5] = BtBig + (size_t)5120 * 1024; pa.sstride[5] = 1024;
    for (int s = 0; s < 3; s++) {
      pa.src[6 + s] = mcWin + s * 1024; pa.dst[6 + s] = mcWinT + (size_t)s * 1024 * 1024;
      pa.sstride[6 + s] = 3072;
    }
    pa.src[9]  = caWout; pa.dst[9]  = caWoutT; pa.sstride[9]  = 1024;
    pa.src[10] = mcWout; pa.dst[10] = mcWoutT; pa.sstride[10] = 1024;
    pa.src[11] = Wo;     pa.dst[11] = WoT;     pa.sstride[11] = 1024;
    pa.cabin = cabin; pa.bq = bq; pa.bk = bk; pa.bv = bv;
    pa.biasBig = biasBig; pa.lbuf = lbuf;
    prep_weights<<<dim3(32, 32, 13), 256, 0, stream>>>(pa);
  }

  // ---- mega in-proj: causal QK + causal V^T + main QKV in one GEMM
  gemm_in3<<<dim3(48, 32), 256, 0, stream>>>(Xbf, BtBig, biasBig, caQK, Vtb, qkvm);
  // ---- causal branch attention (3-GEMM softmax, fixed max)
  gemm_qk_exp<<<dim3(8, 8, 16), 256, 0, stream>>>(caQK, Pbuf, l_ca, 1.f / 16.f);
  gemm_pv<<<dim3(4, 8, 16), 256, 0, stream>>>(Pbuf, Vtb, l_ca, actx);
  // ---- main gated flash attention
  flash_attn64<<<512, 256, 0, stream>>>(qkvm, modb, ctxm);
  // ctx1 = 0.3*ctxm + 0.7*(actx@caWout + cabout)
  gemm_bt<0, 1, 64><<<dim3(16, 32), 256, 0, stream>>>(actx, caWoutT, cabout, ctxm, 0.7f, 0.3f,
                                                      ctx1, 4096, 1024, 1024);
  // ---- meta branch: in-proj (QK + V^T) then 3-GEMM attention
  gemm_in3<<<dim3(24, 32), 256, 0, stream>>>(ctx1, mcWinT, mcbin, mcQK, Vtb, qkvm /*unused*/);
  gemm_qk_exp<<<dim3(8, 8, 16), 256, 0, stream>>>(mcQK, Pbuf, l_mc, 1.f / 16.f);
  gemm_pv<<<dim3(4, 8, 16), 256, 0, stream>>>(Pbuf, Vtb, l_mc, mctx);
  // ctx2 = 0.85*ctx1 + 0.15*(mctx@mcWout + mcbout)
  gemm_bt<0, 1, 64><<<dim3(16, 32), 256, 0, stream>>>(mctx, mcWoutT, mcbout, ctx1, 0.15f, 0.85f,
                                                      ctx2, 4096, 1024, 1024);
  // out = ctx2@Wo + bo (fp32)
  gemm_bt<1, 0, 64><<<dim3(16, 32), 256, 0, stream>>>(ctx2, WoT, bo, nullptr, 0.f, 0.f,
                                                      d_out, 4096, 1024, 1024);
}

// Round 7
// 432.377 us; speedup vs baseline: 1.3412x; 1.0236x over previous
//
#include <hip/hip_runtime.h>
#include <stdint.h>

typedef unsigned short u16;
typedef __attribute__((ext_vector_type(8))) short short8;    // 8 x bf16 (4 VGPRs)
typedef __attribute__((ext_vector_type(4))) float f32x4;     // 16x16 MFMA acc
typedef __attribute__((ext_vector_type(16))) float f32x16;   // 32x32 MFMA acc

#define MFMA16(a,b,c) __builtin_amdgcn_mfma_f32_16x16x32_bf16((a),(b),(c),0,0,0)
#define MFMA32(a,b,c) __builtin_amdgcn_mfma_f32_32x32x16_bf16((a),(b),(c),0,0,0)

__device__ __forceinline__ float fast_exp2(float x) {
  return __builtin_amdgcn_exp2f(x);   // v_exp_f32: D = 2^S0
}

__device__ __forceinline__ u16 f2bf(float f) {
  union { float f; uint32_t u; } v; v.f = f;
  uint32_t r = v.u + 0x7FFFu + ((v.u >> 16) & 1u);   // RNE
  return (u16)(r >> 16);
}
__device__ __forceinline__ float bf2f(uint32_t u) {
  union { uint32_t i; float f; } v; v.i = u << 16; return v.f;
}
// async global->LDS, 16B per lane; LDS dest = wave-uniform base + lane*16
__device__ __forceinline__ void async_copy16(void* lds, const void* g) {
  __builtin_amdgcn_global_load_lds(
      (const __attribute__((address_space(1))) uint32_t*)g,
      (__attribute__((address_space(3))) uint32_t*)lds, 16, 0, 0);
}

// in-register 8x8 u16 transpose across 8 lanes (lane8 = lane&7), 4 u32 regs
__device__ __forceinline__ void transpose8x8(uint32_t r[4], int lane8) {
  uint32_t a0, a1, a2, a3;
  a0 = __shfl_xor(r[0], 4); a1 = __shfl_xor(r[1], 4);
  a2 = __shfl_xor(r[2], 4); a3 = __shfl_xor(r[3], 4);
  if (lane8 & 4) { r[0] = a2; r[1] = a3; } else { r[2] = a0; r[3] = a1; }
  a0 = __shfl_xor(r[0], 2); a1 = __shfl_xor(r[1], 2);
  a2 = __shfl_xor(r[2], 2); a3 = __shfl_xor(r[3], 2);
  if (lane8 & 2) { r[0] = a1; r[2] = a3; } else { r[1] = a0; r[3] = a2; }
  a0 = __shfl_xor(r[0], 1); a1 = __shfl_xor(r[1], 1);
  a2 = __shfl_xor(r[2], 1); a3 = __shfl_xor(r[3], 1);
  uint32_t sel = (lane8 & 1) ? 0x03020706u : 0x05040100u;
  r[0] = __builtin_amdgcn_perm(a0, r[0], sel);
  r[1] = __builtin_amdgcn_perm(a1, r[1], sel);
  r[2] = __builtin_amdgcn_perm(a2, r[2], sel);
  r[3] = __builtin_amdgcn_perm(a3, r[3], sel);
}

// ---------------------------------------------------------------------------
// fused: Xbf = bf16(X);  mod = sigmoid(...)*0.125*log2e  (flash uses exp2)
__global__ __launch_bounds__(256) void castmod_kernel(
    const float* __restrict__ X, u16* __restrict__ Xbf,
    const float* __restrict__ cgW, const float* __restrict__ cgb,
    const float* __restrict__ cons, const float* __restrict__ amW,
    const float* __restrict__ amb, float* __restrict__ modp) {
  __shared__ float xs[1024];
  __shared__ float part[16][16];
  __shared__ float am[16];
  int row = blockIdx.x, t = threadIdx.x;
  {
    float4 v = ((const float4*)(X + (size_t)row * 1024))[t];
    xs[t * 4 + 0] = v.x; xs[t * 4 + 1] = v.y; xs[t * 4 + 2] = v.z; xs[t * 4 + 3] = v.w;
    uint2 o;
    o.x = (uint32_t)f2bf(v.x) | ((uint32_t)f2bf(v.y) << 16);
    o.y = (uint32_t)f2bf(v.z) | ((uint32_t)f2bf(v.w) << 16);
    ((uint2*)Xbf)[(size_t)row * 256 + t] = o;
  }
  if (t < 16) {
    float a = amb[t];
#pragma unroll
    for (int i = 0; i < 16; i++) a += cons[i] * amW[i * 16 + t];
    am[t] = a;
  }
  __syncthreads();
  int h = t & 15, ch = t >> 4;
  float p = 0.f;
#pragma unroll 8
  for (int k = ch * 64; k < ch * 64 + 64; k++) p += xs[k] * cgW[k * 16 + h];
  part[ch][h] = p;
  __syncthreads();
  if (t < 16) {
    float s = cgb[t] + am[t];
#pragma unroll
    for (int c = 0; c < 16; c++) s += part[c][t];
    int b = row >> 10, si = row & 1023;
    // 0.125 * log2(e) = 0.1803368801111...
    modp[((size_t)(b * 16 + t)) * 1024 + si] = 0.18033688f / (1.f + __expf(-s));
  }
}

// ---------------------------------------------------------------------------
// all weight prep in one kernel: 12 transpose+cast slices (z<12) + misc (z=12)
struct PrepArgs {
  const float* src[12];
  u16* dst[12];
  int sstride[12];
  const float* cabin; const float* bq; const float* bk; const float* bv;
  float* biasBig; float* lbuf;
};
__global__ __launch_bounds__(256) void prep_weights(PrepArgs p) {
  int z = blockIdx.z;
  int tx = threadIdx.x & 31, ty = threadIdx.x >> 5;   // (32,8) logical
  if (z < 12) {
    __shared__ float tile[32][33];
    const float* __restrict__ in = p.src[z];
    u16* __restrict__ out = p.dst[z];
    int sstr = p.sstride[z];
    int c0 = blockIdx.x * 32, r0 = blockIdx.y * 32;
#pragma unroll
    for (int j = 0; j < 4; j++)
      tile[ty + j * 8][tx] = in[(size_t)(r0 + ty + j * 8) * sstr + c0 + tx];
    __syncthreads();
#pragma unroll
    for (int j = 0; j < 4; j++)
      out[(size_t)(c0 + ty + j * 8) * 1024 + r0 + tx] = f2bf(tile[tx][ty + j * 8]);
  } else {
    int id = blockIdx.y * 32 + blockIdx.x, t = threadIdx.x;
    if (id < 24) {
      int i = id * 256 + t;   // 0..6143
      float v;
      if (i < 3072) v = p.cabin[i];
      else if (i < 4096) v = p.bq[i - 3072];
      else if (i < 5120) v = p.bk[i - 4096];
      else v = p.bv[i - 5120];
      p.biasBig[i] = v;
    } else if (id < 152) {
      p.lbuf[(id - 24) * 256 + t] = 0.f;
    }
  }
}

// ---------------------------------------------------------------------------
// bf16 GEMM, BK=64: C[M,N] = A[M,K] @ Bt[N,K]^T (+bias, optional blend)
template <int OUT_F32, int HAS_EXTRA, int BN>
__global__ __launch_bounds__(256, 3) void gemm_bt(
    const u16* __restrict__ A, const u16* __restrict__ Bt,
    const float* __restrict__ bias, const u16* __restrict__ extra,
    float alpha, float beta, void* __restrict__ Cout, int M, int N, int K) {
  constexpr int NJ = BN / 32;
  __shared__ u16 As[128 * 64];
  __shared__ u16 Bs[BN * 64];
  const int t = threadIdx.x;
  const int w = t >> 6, l = t & 63, lm = l & 15, lg = l >> 4;
  const int wm = w & 1, wn = w >> 1;
  const int m0 = blockIdx.y * 128, n0 = blockIdx.x * BN;
  const int rl = l >> 3, gsrc8 = ((l & 7) ^ (rl & 7)) * 8;
  const f32x4 fzero = {0.f, 0.f, 0.f, 0.f};
  f32x4 acc[4][NJ];
#pragma unroll
  for (int i = 0; i < 4; i++)
#pragma unroll
    for (int j = 0; j < NJ; j++) acc[i][j] = fzero;

  for (int kt = 0; kt < K; kt += 64) {
    __syncthreads();
#pragma unroll
    for (int c = 0; c < 4; c++) {
      int rb = c * 32 + w * 8;
      async_copy16(&As[rb * 64], A + (size_t)(m0 + rb + rl) * K + kt + gsrc8);
    }
#pragma unroll
    for (int c = 0; c < BN / 32; c++) {
      int rb = c * 32 + w * 8;
      async_copy16(&Bs[rb * 64], Bt + (size_t)(n0 + rb + rl) * K + kt + gsrc8);
    }
    __syncthreads();
#pragma unroll
    for (int kk = 0; kk < 2; kk++) {
      short8 af[4], bf[NJ];
      const int gph = ((kk * 4 + lg) ^ (lm & 7)) * 8;
#pragma unroll
      for (int i = 0; i < 4; i++)
        af[i] = *(const short8*)&As[(wm * 64 + i * 16 + lm) * 64 + gph];
#pragma unroll
      for (int j = 0; j < NJ; j++)
        bf[j] = *(const short8*)&Bs[(wn * (BN / 2) + j * 16 + lm) * 64 + gph];
#pragma unroll
      for (int i = 0; i < 4; i++)
#pragma unroll
        for (int j = 0; j < NJ; j++) acc[i][j] = MFMA16(af[i], bf[j], acc[i][j]);
    }
  }
#pragma unroll
  for (int i = 0; i < 4; i++) {
    int row0 = m0 + wm * 64 + i * 16 + lg * 4;
#pragma unroll
    for (int j = 0; j < NJ; j++) {
      int col = n0 + wn * (BN / 2) + j * 16 + lm;
      float bc = bias[col];
#pragma unroll
      for (int r = 0; r < 4; r++) {
        size_t idx = (size_t)(row0 + r) * N + col;
        float v = acc[i][j][r] + bc;
        if constexpr (HAS_EXTRA) v = alpha * v + beta * bf2f(extra[idx]);
        if constexpr (OUT_F32) ((float*)Cout)[idx] = v;
        else ((u16*)Cout)[idx] = f2bf(v);
      }
    }
  }
}

// ---------------------------------------------------------------------------
// mega in-projection: epilogue routes by column region (see round-4 notes)
__global__ __launch_bounds__(256, 3) void gemm_in3(
    const u16* __restrict__ A, const u16* __restrict__ BtBig,
    const float* __restrict__ bias, u16* __restrict__ qkOut,
    u16* __restrict__ Vtb, u16* __restrict__ qkvm) {
  constexpr int K = 1024;
  __shared__ u16 As[128 * 64];
  __shared__ u16 Bs[128 * 64];
  const int t = threadIdx.x;
  const int w = t >> 6, l = t & 63, lm = l & 15, lg = l >> 4;
  const int wm = w & 1, wn = w >> 1;
  const int m0 = blockIdx.y * 128, n0 = blockIdx.x * 128;
  const int rl = l >> 3, gsrc8 = ((l & 7) ^ (rl & 7)) * 8;
  const f32x4 fzero = {0.f, 0.f, 0.f, 0.f};
  f32x4 acc[4][4];
#pragma unroll
  for (int i = 0; i < 4; i++)
#pragma unroll
    for (int j = 0; j < 4; j++) acc[i][j] = fzero;

  for (int kt = 0; kt < K; kt += 64) {
    __syncthreads();
#pragma unroll
    for (int c = 0; c < 4; c++) {
      int rb = c * 32 + w * 8;
      async_copy16(&As[rb * 64], A + (size_t)(m0 + rb + rl) * K + kt + gsrc8);
      async_copy16(&Bs[rb * 64], BtBig + (size_t)(n0 + rb + rl) * K + kt + gsrc8);
    }
    __syncthreads();
#pragma unroll
    for (int kk = 0; kk < 2; kk++) {
      short8 af[4], bf[4];
      const int gph = ((kk * 4 + lg) ^ (lm & 7)) * 8;
#pragma unroll
      for (int i = 0; i < 4; i++)
        af[i] = *(const short8*)&As[(wm * 64 + i * 16 + lm) * 64 + gph];
#pragma unroll
      for (int j = 0; j < 4; j++)
        bf[j] = *(const short8*)&Bs[(wn * 64 + j * 16 + lm) * 64 + gph];
#pragma unroll
      for (int i = 0; i < 4; i++)
#pragma unroll
        for (int j = 0; j < 4; j++) acc[i][j] = MFMA16(af[i], bf[j], acc[i][j]);
    }
  }
#pragma unroll
  for (int i = 0; i < 4; i++) {
    int row0 = m0 + wm * 64 + i * 16 + lg * 4;
#pragma unroll
    for (int j = 0; j < 4; j++) {
      int col = n0 + wn * 64 + j * 16 + lm;
      float bc = bias[col];
      if (col < 2048) {
#pragma unroll
        for (int r = 0; r < 4; r++)
          qkOut[(size_t)(row0 + r) * 2048 + col] = f2bf(acc[i][j][r] + bc);
      } else if (col < 3072) {
        int b = row0 >> 10, q0 = row0 & 1023;
        int z = b * 4 + ((col - 2048) >> 8), d = (col - 2048) & 255;
        union { u16 pk[4]; uint2 v; } u;
#pragma unroll
        for (int r = 0; r < 4; r++) u.pk[r] = f2bf(acc[i][j][r] + bc);
        *(uint2*)&Vtb[((size_t)z * 256 + d) * 1024 + q0] = u.v;
      } else {
#pragma unroll
        for (int r = 0; r < 4; r++)
          qkvm[(size_t)(row0 + r) * 3072 + col - 3072] = f2bf(acc[i][j][r] + bc);
      }
    }
  }
}

// ---------------------------------------------------------------------------
// QK^T body with exp2 epilogue + fused row-sum atomics (fixed-max softmax).
// smem must provide 2 * 128*64 u16. scale2 = scale * log2(e).
__device__ __forceinline__ void qk_body(
    char* smem, const u16* __restrict__ qk, u16* __restrict__ P,
    float* __restrict__ lrow, float scale2, int nb, int mb, int z) {
  constexpr int QKS = 2048;
  u16* As = (u16*)smem;
  u16* Bs = (u16*)(smem + 128 * 64 * 2);
  const int t = threadIdx.x;
  const int w = t >> 6, l = t & 63, lm = l & 15, lg = l >> 4;
  const int wm = w & 1, wn = w >> 1;
  const int b = z >> 2, h = z & 3;
  const int m0 = mb * 128, n0 = nb * 128;
  const u16* Abase = qk + ((size_t)b << 10) * QKS + h * 256;          // Q
  const u16* Bbase = qk + ((size_t)b << 10) * QKS + 1024 + h * 256;   // K
  const int rl = l >> 3, gsrc8 = ((l & 7) ^ (rl & 7)) * 8;
  const f32x4 fzero = {0.f, 0.f, 0.f, 0.f};
  f32x4 acc[4][4];
#pragma unroll
  for (int i = 0; i < 4; i++)
#pragma unroll
    for (int j = 0; j < 4; j++) acc[i][j] = fzero;

#pragma unroll
  for (int kt = 0; kt < 256; kt += 64) {
    __syncthreads();
#pragma unroll
    for (int c = 0; c < 4; c++) {
      int rb = c * 32 + w * 8;
      async_copy16(&As[rb * 64], Abase + (size_t)(m0 + rb + rl) * QKS + kt + gsrc8);
      async_copy16(&Bs[rb * 64], Bbase + (size_t)(n0 + rb + rl) * QKS + kt + gsrc8);
    }
    __syncthreads();
#pragma unroll
    for (int kk = 0; kk < 2; kk++) {
      short8 af[4], bf[4];
      const int gph = ((kk * 4 + lg) ^ (lm & 7)) * 8;
#pragma unroll
      for (int i = 0; i < 4; i++)
        af[i] = *(const short8*)&As[(wm * 64 + i * 16 + lm) * 64 + gph];
#pragma unroll
      for (int j = 0; j < 4; j++)
        bf[j] = *(const short8*)&Bs[(wn * 64 + j * 16 + lm) * 64 + gph];
#pragma unroll
      for (int i = 0; i < 4; i++)
#pragma unroll
        for (int j = 0; j < 4; j++) acc[i][j] = MFMA16(af[i], bf[j], acc[i][j]);
    }
  }
  u16* Pz = P + ((size_t)z << 20);
#pragma unroll
  for (int i = 0; i < 4; i++) {
    int row0 = m0 + wm * 64 + i * 16 + lg * 4;
    float rsum[4] = {0.f, 0.f, 0.f, 0.f};
#pragma unroll
    for (int j = 0; j < 4; j++) {
      int col = n0 + wn * 64 + j * 16 + lm;
#pragma unroll
      for (int r = 0; r < 4; r++) {
        float p = fast_exp2(acc[i][j][r] * scale2);
        rsum[r] += p;
        Pz[(size_t)(row0 + r) * 1024 + col] = f2bf(p);
      }
    }
#pragma unroll
    for (int r = 0; r < 4; r++) {
      float s = rsum[r];
#pragma unroll
      for (int sh = 1; sh <= 8; sh <<= 1) s += __shfl_xor(s, sh);
      if (lm == 0) atomicAdd(&lrow[(z << 10) + row0 + r], s);
    }
  }
}

// standalone qk kernel (meta phase)
__global__ __launch_bounds__(256, 3) void gemm_qk_exp(
    const u16* __restrict__ qk, u16* __restrict__ P, float* __restrict__ lrow,
    float scale2) {
  __shared__ char smem[2 * 128 * 64 * 2];
  qk_body(smem, qk, P, lrow, scale2, blockIdx.x, blockIdx.y, blockIdx.z);
}

// ---------------------------------------------------------------------------
// flash body, 32x32x16 MFMA. HD=64, NH=16, S=1024, BQ=128 (32 q-rows/wave),
// BKV=128, fixed-max exp2 softmax. smem needs 16K + 17408 + 34816 = 68.2 KB.
__device__ __forceinline__ void flash_body(
    char* smem, const u16* __restrict__ qkv, const float* __restrict__ modp,
    u16* __restrict__ outp, int fid) {
  constexpr int S = 1024, W3 = 3072, HD = 64, BKV = 128;
  constexpr int VSTR = 136, PSTR = 136;
  u16* Ks = (u16*)smem;                         // 128 x 64
  u16* Vt = (u16*)(smem + 16384);               // 64 x 136
  u16* Ps = (u16*)(smem + 16384 + 17408);       // 128 x 136

  const int t = threadIdx.x, w = t >> 6, l = t & 63, l31 = l & 31, hl = l >> 5;
  const int rest = fid >> 3;
  const int q0 = (rest & 7) * 128;
  const int bh = (fid & 7) + 8 * (rest >> 3);    // 0..63, XCD-grouped
  const int b = bh >> 4, h = bh & 15;
  const size_t rowbase = (size_t)b * S;
  const int qw = q0 + w * 32;

  const int oc = t >> 3, kvo = t & 7;
  const int sd0 = (oc & 7) * 8;
  const int skvg = (oc >> 3) * 8;

  // Q fragments: A[m=l31][k = ks*16 + hl*8 + j]
  short8 qf[4];
  {
    const u16* qp = qkv + (rowbase + qw + l31) * W3 + h * HD + hl * 8;
#pragma unroll
    for (int ks = 0; ks < 4; ks++) qf[ks] = *(const short8*)(qp + ks * 16);
  }
  // per-acc-reg row scale (modp pre-scaled by log2e) and lazy row sums
  float rs[16], lsum[16];
#pragma unroll
  for (int reg = 0; reg < 16; reg++) {
    int qloc = (reg & 3) + 8 * (reg >> 2) + 4 * hl;
    rs[reg] = modp[(size_t)bh * S + qw + qloc];
    lsum[reg] = 0.f;
  }
  f32x16 oacc[2];
#pragma unroll
  for (int d = 0; d < 2; d++)
#pragma unroll
    for (int i = 0; i < 16; i++) oacc[d][i] = 0.f;

  for (int kb = 0; kb < S; kb += BKV) {
    __syncthreads();
    // ---- stage K: async DMA, XOR-granule swizzle on global side
#pragma unroll
    for (int c = 0; c < 4; c++) {
      int rb = c * 32 + w * 8;
      int row = rb + (l >> 3);
      int gsrc = ((l & 7) ^ (row & 7)) * 8;
      async_copy16(&Ks[rb * HD],
                   qkv + (rowbase + kb + row) * W3 + 1024 + h * HD + gsrc);
    }
    // ---- stage V transposed via in-register 8x8 butterfly
#pragma unroll
    for (int c = 0; c < 4; c++) {
      int kv = c * 32 + skvg + kvo;
      union { short8 s; uint32_t u[4]; } vv, vo;
      vv.s = *(const short8*)(qkv + (rowbase + kb + kv) * W3 + 2048 + h * HD + sd0);
      uint32_t r[4] = {vv.u[0], vv.u[1], vv.u[2], vv.u[3]};
      transpose8x8(r, kvo);
      vo.u[0] = r[0]; vo.u[1] = r[1]; vo.u[2] = r[2]; vo.u[3] = r[3];
      *(short8*)&Vt[(sd0 + kvo) * VSTR + c * 32 + skvg] = vo.s;
    }
    __syncthreads();

    // ---- S = Q K^T : 4 n32-tiles x 4 ksteps of 32x32x16
    f32x16 sacc[4];
#pragma unroll
    for (int n = 0; n < 4; n++)
#pragma unroll
      for (int i = 0; i < 16; i++) sacc[n][i] = 0.f;
#pragma unroll
    for (int n = 0; n < 4; n++) {
      int krow = n * 32 + l31;
#pragma unroll
      for (int ks = 0; ks < 4; ks++) {
        int g = ks * 2 + hl;
        short8 kf = *(const short8*)&Ks[krow * HD + ((g ^ (krow & 7)) * 8)];
        sacc[n] = MFMA32(qf[ks], kf, sacc[n]);
      }
    }
    // ---- p = exp2(s*mod'), lazy l, P -> LDS (same-wave rows only)
#pragma unroll
    for (int n = 0; n < 4; n++) {
#pragma unroll
      for (int reg = 0; reg < 16; reg++) {
        float p = fast_exp2(sacc[n][reg] * rs[reg]);
        lsum[reg] += p;
        int qloc = (reg & 3) + 8 * (reg >> 2) + 4 * hl;
        Ps[(w * 32 + qloc) * PSTR + n * 32 + l31] = f2bf(p);
      }
    }
    // ---- O += P V : 8 ksteps, A=P[q][k], B=Vt[d][k]
#pragma unroll
    for (int ks = 0; ks < 8; ks++) {
      short8 pa = *(const short8*)&Ps[(w * 32 + l31) * PSTR + ks * 16 + hl * 8];
#pragma unroll
      for (int d = 0; d < 2; d++) {
        short8 vb = *(const short8*)&Vt[(d * 32 + l31) * VSTR + ks * 16 + hl * 8];
        oacc[d] = MFMA32(pa, vb, oacc[d]);
      }
    }
  }
  // ---- reduce l across the 32-lane half (cols), normalize, store
  float invl[16];
#pragma unroll
  for (int reg = 0; reg < 16; reg++) {
    float s = lsum[reg];
#pragma unroll
    for (int sh = 1; sh <= 16; sh <<= 1) s += __shfl_xor(s, sh);
    invl[reg] = 1.f / s;
  }
#pragma unroll
  for (int d = 0; d < 2; d++) {
#pragma unroll
    for (int reg = 0; reg < 16; reg++) {
      int qloc = (reg & 3) + 8 * (reg >> 2) + 4 * hl;
      outp[(rowbase + qw + qloc) * 1024 + h * HD + d * 32 + l31] =
          f2bf(oacc[d][reg] * invl[reg]);
    }
  }
}

// ---------------------------------------------------------------------------
// fused dispatch: 1536 blocks; every 3rd block runs the flash path (512),
// the rest run causal-QK exp GEMM (1024). Both consume gemm_in3's outputs,
// so they are independent and co-resident per CU (m114 co-scheduling).
__global__ __launch_bounds__(256, 2) void fused_qk_flash(
    const u16* __restrict__ qkvm, const float* __restrict__ modp,
    u16* __restrict__ ctxm, const u16* __restrict__ caQK,
    u16* __restrict__ P, float* __restrict__ lrow, float scale2) {
  __shared__ char smem[16384 + 17408 + 34816];   // 68.2 KB
  const int bid = blockIdx.x;
  const int q3 = bid / 3, m3 = bid - q3 * 3;
  if (m3 == 2) {
    flash_body(smem, qkvm, modp, ctxm, q3);
  } else {
    int qid = q3 * 2 + m3;                       // 0..1023
    qk_body(smem, caQK, P, lrow, scale2, qid & 7, (qid >> 3) & 7, qid >> 6);
  }
}

// ---------------------------------------------------------------------------
// batched PV: O[q][d] = (P[z] @ Vtb[z]^T) / l -> ctx[B*S][1024] at col h*256
__global__ __launch_bounds__(256, 3) void gemm_pv(
    const u16* __restrict__ P, const u16* __restrict__ Vtb,
    const float* __restrict__ lrow, u16* __restrict__ outp) {
  constexpr int K = 1024, BN = 64, NJ = 2;
  __shared__ u16 As[128 * 64];
  __shared__ u16 Bs[BN * 64];
  const int t = threadIdx.x;
  const int w = t >> 6, l = t & 63, lm = l & 15, lg = l >> 4;
  const int wm = w & 1, wn = w >> 1;
  const int z = blockIdx.z, b = z >> 2, h = z & 3;
  const int m0 = blockIdx.y * 128, n0 = blockIdx.x * BN;
  const u16* Abase = P + ((size_t)z << 20);
  const u16* Bbase = Vtb + ((size_t)z << 18);
  const int rl = l >> 3, gsrc8 = ((l & 7) ^ (rl & 7)) * 8;
  const f32x4 fzero = {0.f, 0.f, 0.f, 0.f};
  f32x4 acc[4][NJ];
#pragma unroll
  for (int i = 0; i < 4; i++)
#pragma unroll
    for (int j = 0; j < NJ; j++) acc[i][j] = fzero;

  for (int kt = 0; kt < K; kt += 64) {
    __syncthreads();
#pragma unroll
    for (int c = 0; c < 4; c++) {
      int rb = c * 32 + w * 8;
      async_copy16(&As[rb * 64], Abase + (size_t)(m0 + rb + rl) * K + kt + gsrc8);
    }
#pragma unroll
    for (int c = 0; c < BN / 32; c++) {
      int rb = c * 32 + w * 8;
      async_copy16(&Bs[rb * 64], Bbase + (size_t)(n0 + rb + rl) * K + kt + gsrc8);
    }
    __syncthreads();
#pragma unroll
    for (int kk = 0; kk < 2; kk++) {
      short8 af[4], bf[NJ];
      const int gph = ((kk * 4 + lg) ^ (lm & 7)) * 8;
#pragma unroll
      for (int i = 0; i < 4; i++)
        af[i] = *(const short8*)&As[(wm * 64 + i * 16 + lm) * 64 + gph];
#pragma unroll
      for (int j = 0; j < NJ; j++)
        bf[j] = *(const short8*)&Bs[(wn * (BN / 2) + j * 16 + lm) * 64 + gph];
#pragma unroll
      for (int i = 0; i < 4; i++)
#pragma unroll
        for (int j = 0; j < NJ; j++) acc[i][j] = MFMA16(af[i], bf[j], acc[i][j]);
    }
  }
#pragma unroll
  for (int i = 0; i < 4; i++) {
    int row0 = m0 + wm * 64 + i * 16 + lg * 4;
    float invl[4];
#pragma unroll
    for (int r = 0; r < 4; r++) invl[r] = 1.f / lrow[(z << 10) + row0 + r];
#pragma unroll
    for (int j = 0; j < NJ; j++) {
      int col = n0 + wn * (BN / 2) + j * 16 + lm;
#pragma unroll
      for (int r = 0; r < 4; r++)
        outp[(size_t)((b << 10) + row0 + r) * 1024 + h * 256 + col] =
            f2bf(acc[i][j][r] * invl[r]);
    }
  }
}

// ---------------------------------------------------------------------------
extern "C" void kernel_launch(void* const* d_in, const int* in_sizes, int n_in,
                              void* d_out, int out_size, void* d_ws, size_t ws_size,
                              hipStream_t stream) {
  (void)in_sizes; (void)n_in; (void)out_size; (void)ws_size;
  const float* X      = (const float*)d_in[0];
  const float* cons   = (const float*)d_in[1];
  const float* Wq     = (const float*)d_in[2];  const float* bq     = (const float*)d_in[3];
  const float* Wk     = (const float*)d_in[4];  const float* bk     = (const float*)d_in[5];
  const float* Wv     = (const float*)d_in[6];  const float* bv     = (const float*)d_in[7];
  const float* cgW    = (const float*)d_in[8];  const float* cgb    = (const float*)d_in[9];
  const float* amW    = (const float*)d_in[10]; const float* amb    = (const float*)d_in[11];
  const float* caWin  = (const float*)d_in[12]; const float* cabin  = (const float*)d_in[13];
  const float* caWout = (const float*)d_in[14]; const float* cabout = (const float*)d_in[15];
  const float* mcWin  = (const float*)d_in[16]; const float* mcbin  = (const float*)d_in[17];
  const float* mcWout = (const float*)d_in[18]; const float* mcbout = (const float*)d_in[19];
  const float* Wo     = (const float*)d_in[20]; const float* bo     = (const float*)d_in[21];

  char* ws = (char*)d_ws;
  size_t off = 0;
  auto alloc = [&](size_t bytes) -> void* {
    void* p = ws + off; off += (bytes + 255) & ~(size_t)255; return p;
  };
  u16*    Xbf     = (u16*)alloc((size_t)4096 * 1024 * 2);
  u16*    BtBig   = (u16*)alloc((size_t)6144 * 1024 * 2);        // caWin^T | Wqkv^T
  u16*    mcWinT  = (u16*)alloc((size_t)3072 * 1024 * 2);
  u16*    caWoutT = (u16*)alloc((size_t)1024 * 1024 * 2);
  u16*    mcWoutT = (u16*)alloc((size_t)1024 * 1024 * 2);
  u16*    WoT     = (u16*)alloc((size_t)1024 * 1024 * 2);
  float*  biasBig = (float*)alloc(6144 * 4);
  float*  modb    = (float*)alloc((size_t)64 * 1024 * 4);
  u16*    caQK    = (u16*)alloc((size_t)4096 * 2048 * 2);        // also mcQK
  u16*    qkvm    = (u16*)alloc((size_t)4096 * 3072 * 2);
  u16*    actx    = (u16*)alloc((size_t)4096 * 1024 * 2);
  u16*    ctxm    = (u16*)alloc((size_t)4096 * 1024 * 2);
  u16*    ctx1    = (u16*)alloc((size_t)4096 * 1024 * 2);
  u16*    Pbuf    = (u16*)alloc((size_t)16 * 1024 * 1024 * 2);   // 32 MB
  u16*    Vtb     = (u16*)alloc((size_t)16 * 256 * 1024 * 2);    // 8 MB
  float*  lbuf    = (float*)alloc((size_t)2 * 16384 * 4);        // l_ca | l_mc
  float*  l_ca    = lbuf;
  float*  l_mc    = lbuf + 16384;
  u16*    mcQK    = caQK;  // alias: caQK dead after fused qk
  u16*    mctx    = ctxm;  // alias: ctxm dead after blend1
  u16*    ctx2    = actx;  // alias: actx dead after blend1

  const float SC2 = 1.4426950408889634f / 16.f;   // log2(e)/16

  // ---- prep (2 launches)
  castmod_kernel<<<4096, 256, 0, stream>>>(X, Xbf, cgW, cgb, cons, amW, amb, modb);
  {
    PrepArgs pa;
    for (int s = 0; s < 3; s++) {
      pa.src[s] = caWin + s * 1024; pa.dst[s] = BtBig + (size_t)s * 1024 * 1024;
      pa.sstride[s] = 3072;
    }
    pa.src[3] = Wq; pa.dst[3] = BtBig + (size_t)3072 * 1024; pa.sstride[3] = 1024;
    pa.src[4] = Wk; pa.dst[4] = BtBig + (size_t)4096 * 1024; pa.sstride[4] = 1024;
    pa.src[5] = Wv; pa.dst[5] = BtBig + (size_t)5120 * 1024; pa.sstride[5] = 1024;
    for (int s = 0; s < 3; s++) {
      pa.src[6 + s] = mcWin + s * 1024; pa.dst[6 + s] = mcWinT + (size_t)s * 1024 * 1024;
      pa.sstride[6 + s] = 3072;
    }
    pa.src[9]  = caWout; pa.dst[9]  = caWoutT; pa.sstride[9]  = 1024;
    pa.src[10] = mcWout; pa.dst[10] = mcWoutT; pa.sstride[10] = 1024;
    pa.src[11] = Wo;     pa.dst[11] = WoT;     pa.sstride[11] = 1024;
    pa.cabin = cabin; pa.bq = bq; pa.bk = bk; pa.bv = bv;
    pa.biasBig = biasBig; pa.lbuf = lbuf;
    prep_weights<<<dim3(32, 32, 13), 256, 0, stream>>>(pa);
  }

  // ---- mega in-proj: causal QK + causal V^T + main QKV in one GEMM
  gemm_in3<<<dim3(48, 32), 256, 0, stream>>>(Xbf, BtBig, biasBig, caQK, Vtb, qkvm);
  // ---- fused: main flash attention + causal QK-exp GEMM (independent)
  fused_qk_flash<<<1536, 256, 0, stream>>>(qkvm, modb, ctxm, caQK, Pbuf, l_ca, SC2);
  // ---- causal PV
  gemm_pv<<<dim3(4, 8, 16), 256, 0, stream>>>(Pbuf, Vtb, l_ca, actx);
  // ctx1 = 0.3*ctxm + 0.7*(actx@caWout + cabout)
  gemm_bt<0, 1, 64><<<dim3(16, 32), 256, 0, stream>>>(actx, caWoutT, cabout, ctxm, 0.7f, 0.3f,
                                                      ctx1, 4096, 1024, 1024);
  // ---- meta branch
  gemm_in3<<<dim3(24, 32), 256, 0, stream>>>(ctx1, mcWinT, mcbin, mcQK, Vtb, qkvm /*unused*/);
  gemm_qk_exp<<<dim3(8, 8, 16), 256, 0, stream>>>(mcQK, Pbuf, l_mc, SC2);
  gemm_pv<<<dim3(4, 8, 16), 256, 0, stream>>>(Pbuf, Vtb, l_mc, mctx);
  // ctx2 = 0.85*ctx1 + 0.15*(mctx@mcWout + mcbout)
  gemm_bt<0, 1, 64><<<dim3(16, 32), 256, 0, stream>>>(mctx, mcWoutT, mcbout, ctx1, 0.15f, 0.85f,
                                                      ctx2, 4096, 1024, 1024);
  // out = ctx2@Wo + bo (fp32)
  gemm_bt<1, 0, 64><<<dim3(16, 32), 256, 0, stream>>>(ctx2, WoT, bo, nullptr, 0.f, 0.f,
                                                      d_out, 4096, 1024, 1024);
}